// Round 1
// baseline (357.656 us; speedup 1.0000x reference)
//
#include <hip/hip_runtime.h>
#include <hip/hip_bf16.h>

// Problem: B=256, T=64, A=32, H=512, E=32
#define NB 256
#define NT 64
#define NA 32
#define NH 512
#define NE 32
#define MAXTILES 144   // max sum_e ceil(count_e/2) = 128 + 16

typedef short short8 __attribute__((ext_vector_type(8)));
typedef unsigned short ushort8v __attribute__((ext_vector_type(8)));
typedef float f32x4 __attribute__((ext_vector_type(4)));

__device__ __forceinline__ unsigned short f2bf(float f) {
  unsigned int u = __float_as_uint(f);
  u += 0x7FFFu + ((u >> 16) & 1u);   // round-to-nearest-even
  return (unsigned short)(u >> 16);
}

// async global->LDS, 16B per lane; lds dest = wave-uniform base + lane*16
__device__ __forceinline__ void gl2lds16(const void* g, void* l) {
  __builtin_amdgcn_global_load_lds(
      (const __attribute__((address_space(1))) unsigned int*)g,
      (__attribute__((address_space(3))) unsigned int*)l, 16, 0, 0);
}

// ---------------------------------------------------------------------------
// groupk: bucket samples by expert; tiles of 2 same-expert samples.
// Also emits order/off/cnt to global for the tvec kernel.
// ---------------------------------------------------------------------------
__global__ __launch_bounds__(256) void groupk(const int* __restrict__ cat,
                                              int* __restrict__ tiles,
                                              int* __restrict__ ntiles_out,
                                              int* __restrict__ orderG,
                                              int* __restrict__ offG,
                                              int* __restrict__ cntG) {
  __shared__ int cnt[NE], off[NE], cur[NE];
  __shared__ int order[NB];
  int tid = threadIdx.x;
  if (tid < NE) cnt[tid] = 0;
  __syncthreads();
  int e = cat[tid];
  atomicAdd(&cnt[e], 1);
  __syncthreads();
  if (tid == 0) {
    int s = 0;
    for (int i = 0; i < NE; i++) { off[i] = s; cur[i] = s; s += cnt[i]; }
  }
  __syncthreads();
  int p = atomicAdd(&cur[e], 1);
  order[p] = tid;
  __syncthreads();
  orderG[tid] = order[tid];
  if (tid < NE) { offG[tid] = off[tid]; cntG[tid] = cnt[tid]; }
  if (tid == 0) {
    int nt = 0;
    for (int i = 0; i < NE; i++) {
      for (int j = 0; j < cnt[i]; j += 2) {
        tiles[3 * nt + 0] = i;
        tiles[3 * nt + 1] = order[off[i] + j];
        tiles[3 * nt + 2] = (j + 1 < cnt[i]) ? order[off[i] + j + 1] : -1;
        nt++;
      }
    }
    *ntiles_out = nt;
  }
}

// ---------------------------------------------------------------------------
// prep: W fp32 [e][K][N=512] -> Wt bf16 [e][N][K]  (transpose + convert)
// grid: (N/64, ceil(K/64), E)   -- used only for W3 now.
// ---------------------------------------------------------------------------
__global__ __launch_bounds__(256) void prep_kernel(const float* __restrict__ W,
                                                   unsigned short* __restrict__ Wt,
                                                   int K) {
  __shared__ float S[64 * 66];
  int e = blockIdx.z;
  int nt = blockIdx.x * 64;
  int kt = blockIdx.y * 64;
  int TK = (K - kt) < 64 ? (K - kt) : 64;
  int tid = threadIdx.x;
  int units = TK * 32;  // float2 units
  for (int u = tid; u < units; u += 256) {
    int k = u >> 5, c = u & 31;
    float2 v = *(const float2*)(W + ((size_t)e * K + kt + k) * NH + nt + 2 * c);
    *(float2*)(&S[k * 66 + 2 * c]) = v;
  }
  __syncthreads();
  int csh = (TK == 64) ? 3 : 2;
  int CHm = (1 << csh) - 1;
  int wunits = 64 << csh;
  for (int u = tid; u < wunits; u += 256) {
    int n = u >> csh, c = u & CHm;
    ushort8v pk;
#pragma unroll
    for (int j = 0; j < 8; j++) pk[j] = f2bf(S[(c * 8 + j) * 66 + n]);
    *(ushort8v*)(Wt + ((size_t)e * NH + nt + n) * K + kt + c * 8) = pk;
  }
}

// ---------------------------------------------------------------------------
// w12: per expert, fuse the first two linear layers:
//   W12[e][a][n]  = sum_k W1[e][a][k] * W2[e][k][n]      (k,a over 512,32)
//   bias2[e][n]   = sum_k b1[e][k]   * W2[e][k][n] + b2[e][n]
// Output Wt12 bf16 [e][n][a] (same layout the K=32 MFMA staging expects).
// grid (8, NE): Nb=64 n-cols per block; fp32 accumulation (precision).
// ---------------------------------------------------------------------------
__global__ __launch_bounds__(256) void w12_kernel(
    const float* __restrict__ W1, const float* __restrict__ b1,
    const float* __restrict__ W2, const float* __restrict__ b2,
    unsigned short* __restrict__ Wt12, float* __restrict__ bias2) {
  __shared__ float S[128 * 36];  // 18KB: W1T chunk [kk][a], reused as T2[n][a]
  int e = blockIdx.y, n0 = blockIdx.x * 64;
  int tid = threadIdx.x;
  int quad = tid & 15, ag = tid >> 4;   // n = n0+quad*4+j ; a = ag*2+i
  f32x4 acc[2];
  acc[0] = (f32x4){0.f, 0.f, 0.f, 0.f};
  acc[1] = (f32x4){0.f, 0.f, 0.f, 0.f};
  f32x4 accB = (f32x4){0.f, 0.f, 0.f, 0.f};

  for (int c4 = 0; c4 < 4; c4++) {   // K=512 in chunks of 128
    int k0 = c4 * 128;
    __syncthreads();
    // stage W1T[kk][a]: a in [0,33), row 32 = b1
    for (int u = tid; u < 33 * 32; u += 256) {
      int a = u >> 5, g = u & 31;
      const float* src = (a < 32) ? (W1 + ((size_t)e * NA + a) * NH + k0 + g * 4)
                                  : (b1 + (size_t)e * NH + k0 + g * 4);
      float4 v = *(const float4*)src;
      S[(g * 4 + 0) * 36 + a] = v.x;
      S[(g * 4 + 1) * 36 + a] = v.y;
      S[(g * 4 + 2) * 36 + a] = v.z;
      S[(g * 4 + 3) * 36 + a] = v.w;
    }
    __syncthreads();
    const float* w2p = W2 + ((size_t)e * 1024 + k0) * NH + n0 + quad * 4;
#pragma unroll 4
    for (int kk = 0; kk < 128; kk++) {
      f32x4 w2 = *(const f32x4*)(w2p + (size_t)kk * NH);
      float wa0 = S[kk * 36 + ag * 2 + 0];
      float wa1 = S[kk * 36 + ag * 2 + 1];
#pragma unroll
      for (int j = 0; j < 4; j++) {
        acc[0][j] += wa0 * w2[j];
        acc[1][j] += wa1 * w2[j];
      }
      if (ag == 0) {
        float wb = S[kk * 36 + 32];
#pragma unroll
        for (int j = 0; j < 4; j++) accB[j] += wb * w2[j];
      }
    }
  }
  __syncthreads();
  // T2[n][a] = W12[a][n] (LDS transpose; S reused)
#pragma unroll
  for (int i = 0; i < 2; i++)
#pragma unroll
    for (int j = 0; j < 4; j++)
      S[(quad * 4 + j) * 36 + ag * 2 + i] = acc[i][j];
  if (ag == 0) {
    float4 bs = *(const float4*)(b2 + (size_t)e * NH + n0 + quad * 4);
    float* dst = bias2 + (size_t)e * NH + n0 + quad * 4;
    dst[0] = accB[0] + bs.x;
    dst[1] = accB[1] + bs.y;
    dst[2] = accB[2] + bs.z;
    dst[3] = accB[3] + bs.w;
  }
  __syncthreads();
  {  // emit Wt12[e][n][a] bf16 rows (32 a = 64B/row), coalesced 16B stores
    int n = tid >> 2, qtr = tid & 3;
    f32x4 v0 = *(const f32x4*)(&S[n * 36 + qtr * 8]);
    f32x4 v1 = *(const f32x4*)(&S[n * 36 + qtr * 8 + 4]);
    ushort8v p;
#pragma unroll
    for (int j = 0; j < 4; j++) p[j] = f2bf(v0[j]);
#pragma unroll
    for (int j = 0; j < 4; j++) p[4 + j] = f2bf(v1[j]);
    *(ushort8v*)(Wt12 + ((size_t)e * NH + n0 + n) * NA + qtr * 8) = p;
  }
}

// ---------------------------------------------------------------------------
// tvec: per-sample tau contribution (constant over T!):
//   tvec[b][n] = sum_k tau_b[k] * W2[e_b][512+k][n] + bias2[e_b][n]
// Samples grouped by expert so each expert's W2b slice is streamed once
// (chunks of 16 samples). grid (8, NE), Nb=64. Pure fp32.
// ---------------------------------------------------------------------------
__global__ __launch_bounds__(256) void tvec_kernel(
    const int* __restrict__ timesteps, const float* __restrict__ W2,
    const float* __restrict__ bias2, const int* __restrict__ orderG,
    const int* __restrict__ offG, const int* __restrict__ cntG,
    float* __restrict__ tvec) {
  __shared__ float tauS[512 * 16];  // [k][16 samples] 32KB
  int e = blockIdx.y, n0 = blockIdx.x * 64;
  int tid = threadIdx.x;
  int n = tid & 63, sg = tid >> 6;          // sg 0..3; samples s0+sg*4+j
  int c = cntG[e], off = offG[e];
  if (c == 0) return;
  float biasv = bias2[(size_t)e * NH + n0 + n];
  const float kLog = 0.035977893400931146f;  // ln(10000)/256

  for (int s0 = 0; s0 < c; s0 += 16) {
    __syncthreads();
#pragma unroll
    for (int j = 0; j < 32; j++) {  // stage tau for 16 samples
      int u = j * 256 + tid;
      int s = u & 15, k = u >> 4;
      int sglob = s0 + s;
      float v = 0.f;
      if (sglob < c) {
        float t = (float)timesteps[orderG[off + sglob]];
        float f = expf(-(float)(k & 255) * kLog);
        float ang = t * f;
        v = (k < 256) ? sinf(ang) : cosf(ang);
      }
      tauS[k * 16 + s] = v;
    }
    __syncthreads();
    f32x4 acc = (f32x4){0.f, 0.f, 0.f, 0.f};
    const float* w2p = W2 + ((size_t)e * 1024 + 512) * NH + n0 + n;
#pragma unroll 4
    for (int kk = 0; kk < 512; kk++) {
      float w2 = w2p[(size_t)kk * NH];
      f32x4 tf = *(const f32x4*)(&tauS[kk * 16 + sg * 4]);
      acc[0] += tf[0] * w2;
      acc[1] += tf[1] * w2;
      acc[2] += tf[2] * w2;
      acc[3] += tf[3] * w2;
    }
#pragma unroll
    for (int j = 0; j < 4; j++) {
      int s = s0 + sg * 4 + j;
      if (s < c) {
        int b = orderG[off + s];
        tvec[(size_t)b * NH + n0 + n] = acc[j] + biasv;
      }
    }
  }
}

// ---------------------------------------------------------------------------
// gemmh: hidden layer via the FUSED weights. K=32 (one MFMA per fragment):
//   Hb[b*64+t][n] = swish( actions[b][t] @ Wt12[e] + tvec[b][n] )   (bf16 out)
// Structure derived from the verified buildx2 kernel. grid (2, NB).
// ---------------------------------------------------------------------------
__global__ __launch_bounds__(256) void gemmh_kernel(
    const float* __restrict__ actions, const unsigned short* __restrict__ Wt12,
    const float* __restrict__ tvec, const int* __restrict__ cat_ids,
    unsigned short* __restrict__ Hb) {
  __shared__ __align__(16) unsigned char smem[16384 + 5120 + 33792];
  unsigned short* Ws = (unsigned short*)smem;                   // [256][32] swizzled
  unsigned short* As = (unsigned short*)(smem + 16384);         // [64][40]
  unsigned short* Ts = (unsigned short*)(smem + 16384 + 5120);  // [64][264]

  int b = blockIdx.y, h = blockIdx.x;
  int tid = threadIdx.x;
  int e = cat_ids[b];

  {  // async stage Wt12[e][h*256 .. +256][0..32] -> Ws (chunk swizzle)
    const unsigned short* wsrc = Wt12 + ((size_t)e * NH + h * 256) * NA;
#pragma unroll
    for (int j = 0; j < 4; j++) {
      int u = j * 256 + tid;
      int n = u >> 2, p = u & 3;
      int ch = p ^ ((n >> 1) & 3);
      gl2lds16(wsrc + (size_t)n * NA + ch * 8,
               Ws + (size_t)(j * 256 + (tid & 448)) * 8);
    }
  }
  {  // stage actions (64x32 f32 -> bf16), padded stride 40
    int row = tid >> 2, seg = tid & 3;
    const float* src = actions + (size_t)(b * NT + row) * NA + seg * 8;
    float4 v0 = *(const float4*)(src);
    float4 v1 = *(const float4*)(src + 4);
    ushort8v t;
    t[0] = f2bf(v0.x); t[1] = f2bf(v0.y); t[2] = f2bf(v0.z); t[3] = f2bf(v0.w);
    t[4] = f2bf(v1.x); t[5] = f2bf(v1.y); t[6] = f2bf(v1.z); t[7] = f2bf(v1.w);
    *(ushort8v*)(&As[row * 40 + seg * 8]) = t;
  }
  __syncthreads();

  int w = tid >> 6, l = tid & 63;
  int lrow = l & 15, kq = l >> 4;
  short8 af = *(short8*)(&As[(w * 16 + lrow) * 40 + kq * 8]);
  f32x4 zero = {0.f, 0.f, 0.f, 0.f};
  f32x4 acc[16];
#pragma unroll
  for (int ni = 0; ni < 16; ni++) {
    int nn = ni * 16 + lrow;
    int p = kq ^ ((nn >> 1) & 3);
    short8 bfv = *(short8*)(&Ws[nn * 32 + p * 8]);
    acc[ni] = __builtin_amdgcn_mfma_f32_16x16x32_bf16(af, bfv, zero, 0, 0, 0);
  }
#pragma unroll
  for (int ni = 0; ni < 16; ni++) {
    int colL = ni * 16 + lrow;
    float bv = tvec[(size_t)b * NH + h * 256 + colL];  // includes bias2
#pragma unroll
    for (int r = 0; r < 4; r++) {
      int row = w * 16 + kq * 4 + r;
      float v = acc[ni][r] + bv;
      v = v / (1.0f + __expf(-v));  // swish
      Ts[row * 264 + colL] = f2bf(v);
    }
  }
  __syncthreads();
#pragma unroll
  for (int i = 0; i < 8; i++) {  // coalesced Hb rows
    int u = i * 256 + tid;
    int t = u >> 5, c4 = u & 31;
    uint4 v = *(uint4*)(&Ts[t * 264 + c4 * 8]);
    *(uint4*)(Hb + ((size_t)(b * NT + t)) * NH + h * 256 + c4 * 8) = v;
  }
}

// ---------------------------------------------------------------------------
// Grouped GEMM (unchanged, verified): BM=128 x BN=64 x BK=64, 4 waves 2x2,
// global_load_lds staging, XOR-swizzled LDS, LDS-transpose epilogue.
// Instantiated only as the final layer: KTOT=512, fp32 out.
// ---------------------------------------------------------------------------
template <int KTOT, bool HASTAU, bool SWISH, bool OUT_BF16>
__global__ __launch_bounds__(256) void gemm2_kernel(
    const unsigned short* __restrict__ Xa, const unsigned short* __restrict__ Xt,
    const unsigned short* __restrict__ Wt, const float* __restrict__ bias,
    void* __restrict__ Yv, const int* __restrict__ tiles,
    const int* __restrict__ pntiles) {
  constexpr int SMEM = OUT_BF16 ? 24576 : 34816;
  __shared__ __align__(16) unsigned char smem[SMEM];
  unsigned short* As = (unsigned short*)smem;            // [128][64] swizzled
  unsigned short* Bs = (unsigned short*)(smem + 16384);  // [64][64]  swizzled

  int ti = blockIdx.y;
  if (ti >= *pntiles) return;
  int n0 = blockIdx.x * 64;
  int e = tiles[3 * ti], s0 = tiles[3 * ti + 1], s1 = tiles[3 * ti + 2];
  int s1v = (s1 < 0) ? s0 : s1;

  int tid = threadIdx.x;
  int l = tid & 63;
  int wr = (tid >> 7), wc = (tid >> 6) & 1;
  int lrow = l & 15, kq = l >> 4;

  f32x4 acc[4][2];
#pragma unroll
  for (int mi = 0; mi < 4; mi++)
#pragma unroll
    for (int ni = 0; ni < 2; ni++) acc[mi][ni] = (f32x4){0.f, 0.f, 0.f, 0.f};

  const unsigned short* wbase = Wt + ((size_t)e * NH + n0) * KTOT;

  for (int it = 0; it < KTOT / 64; it++) {
    int k0 = it * 64;
    __syncthreads();
#pragma unroll
    for (int j = 0; j < 4; j++) {
      int u = j * 256 + tid;
      int row = u >> 3, p = u & 7;
      int ch = p ^ (row & 7);
      int kk = k0 + ch * 8;
      int s = (row < 64) ? s0 : s1v;
      const unsigned short* src;
      if (HASTAU && kk >= 512)
        src = Xt + (size_t)s * NH + (kk - 512);
      else
        src = Xa + ((size_t)(s * NT + (row & 63))) * NH + kk;
      gl2lds16(src, As + (size_t)(j * 256 + (tid & 448)) * 8);
    }
#pragma unroll
    for (int j = 0; j < 2; j++) {
      int u = j * 256 + tid;
      int n = u >> 3, p = u & 7;
      int ch = p ^ (n & 7);
      gl2lds16(wbase + (size_t)n * KTOT + k0 + ch * 8,
               Bs + (size_t)(j * 256 + (tid & 448)) * 8);
    }
    __syncthreads();

    short8 afr[2][4], bfr[2][2];
#pragma unroll
    for (int s2 = 0; s2 < 2; s2++) {
#pragma unroll
      for (int mi = 0; mi < 4; mi++) {
        int row = wr * 64 + mi * 16 + lrow;
        int p = (s2 * 4 + kq) ^ (row & 7);
        afr[s2][mi] = *(short8*)(&As[row * 64 + p * 8]);
      }
#pragma unroll
      for (int ni = 0; ni < 2; ni++) {
        int n = wc * 32 + ni * 16 + lrow;
        int p = (s2 * 4 + kq) ^ (n & 7);
        bfr[s2][ni] = *(short8*)(&Bs[n * 64 + p * 8]);
      }
    }
#pragma unroll
    for (int s2 = 0; s2 < 2; s2++)
#pragma unroll
      for (int mi = 0; mi < 4; mi++)
#pragma unroll
        for (int ni = 0; ni < 2; ni++)
          acc[mi][ni] = __builtin_amdgcn_mfma_f32_16x16x32_bf16(
              afr[s2][mi], bfr[s2][ni], acc[mi][ni], 0, 0, 0);
  }
  __syncthreads();

#pragma unroll
  for (int ni = 0; ni < 2; ni++) {
    int colL = wc * 32 + ni * 16 + lrow;
    float bv = bias[(size_t)e * NH + n0 + colL];
#pragma unroll
    for (int mi = 0; mi < 4; mi++) {
#pragma unroll
      for (int r = 0; r < 4; r++) {
        int row = wr * 64 + mi * 16 + kq * 4 + r;
        float v = acc[mi][ni][r] + bv;
        if (SWISH) v = v / (1.0f + __expf(-v));
        if (OUT_BF16)
          ((unsigned short*)smem)[row * 80 + colL] = f2bf(v);
        else
          ((float*)smem)[row * 68 + colL] = v;
      }
    }
  }
  __syncthreads();
  if (OUT_BF16) {
    unsigned short* Y = (unsigned short*)Yv;
#pragma unroll
    for (int i = 0; i < 4; i++) {
      int u = i * 256 + tid;
      int row = u >> 3, c = u & 7;
      if (row >= 64 && s1 < 0) continue;
      int s = (row < 64) ? s0 : s1;
      uint4 v = *(uint4*)(&((unsigned short*)smem)[row * 80 + c * 8]);
      *(uint4*)(Y + ((size_t)(s * NT + (row & 63))) * NH + n0 + c * 8) = v;
    }
  } else {
    float* Y = (float*)Yv;
#pragma unroll
    for (int i = 0; i < 8; i++) {
      int u = i * 256 + tid;
      int row = u >> 4, c = u & 15;
      if (row >= 64 && s1 < 0) continue;
      int s = (row < 64) ? s0 : s1;
      uint4 v = *(uint4*)(&((float*)smem)[row * 68 + c * 4]);
      *(uint4*)(Y + ((size_t)(s * NT + (row & 63))) * NH + n0 + c * 4) = v;
    }
  }
}

// ---------------------------------------------------------------------------
extern "C" void kernel_launch(void* const* d_in, const int* in_sizes, int n_in,
                              void* d_out, int out_size, void* d_ws, size_t ws_size,
                              hipStream_t stream) {
  const float* actions   = (const float*)d_in[0];
  const int*   timesteps = (const int*)d_in[1];
  const int*   cat_ids   = (const int*)d_in[2];
  const float* W1 = (const float*)d_in[3];
  const float* b1 = (const float*)d_in[4];
  const float* W2 = (const float*)d_in[5];
  const float* b2 = (const float*)d_in[6];
  const float* W3 = (const float*)d_in[7];
  const float* b3 = (const float*)d_in[8];

  // ws: Hb 16MB | Wt3 16MB | Wt12 1MB | tvec 512KB | bias2 64KB | tiles+order
  unsigned short* Hb   = (unsigned short*)d_ws;
  unsigned short* Wt3  = (unsigned short*)((char*)d_ws + (size_t)16777216);
  unsigned short* Wt12 = (unsigned short*)((char*)d_ws + (size_t)33554432);
  float* tvec  = (float*)((char*)d_ws + (size_t)34603008);
  float* bias2 = (float*)((char*)d_ws + (size_t)35127296);
  int* tiles   = (int*)((char*)d_ws + (size_t)35192832);
  int* ntiles  = tiles + 3 * MAXTILES;
  int* orderG  = ntiles + 1;
  int* offG    = orderG + NB;
  int* cntG    = offG + NE;

  groupk<<<1, 256, 0, stream>>>(cat_ids, tiles, ntiles, orderG, offG, cntG);
  w12_kernel<<<dim3(8, NE), 256, 0, stream>>>(W1, b1, W2, b2, Wt12, bias2);
  tvec_kernel<<<dim3(8, NE), 256, 0, stream>>>(timesteps, W2, bias2, orderG,
                                               offG, cntG, tvec);
  prep_kernel<<<dim3(8, 8, NE), 256, 0, stream>>>(W3, Wt3, 512);
  gemmh_kernel<<<dim3(2, NB), 256, 0, stream>>>(actions, Wt12, tvec, cat_ids, Hb);
  gemm2_kernel<512, false, false, false><<<dim3(8, MAXTILES), 256, 0, stream>>>(
      Hb, nullptr, Wt3, b3, d_out, tiles, ntiles);
}

// Round 2
// 212.578 us; speedup vs baseline: 1.6825x; 1.6825x over previous
//
#include <hip/hip_runtime.h>
#include <hip/hip_bf16.h>

// Problem: B=256, T=64, A=32, H=512, E=32
#define NB 256
#define NT 64
#define NA 32
#define NH 512
#define NE 32
#define MAXTILES 144   // max sum_e ceil(count_e/2) = 128 + 16

typedef short short8 __attribute__((ext_vector_type(8)));
typedef unsigned short ushort8v __attribute__((ext_vector_type(8)));
typedef float f32x4 __attribute__((ext_vector_type(4)));

__device__ __forceinline__ unsigned short f2bf(float f) {
  unsigned int u = __float_as_uint(f);
  u += 0x7FFFu + ((u >> 16) & 1u);   // round-to-nearest-even
  return (unsigned short)(u >> 16);
}

// async global->LDS, 16B per lane; lds dest = wave-uniform base + lane*16
__device__ __forceinline__ void gl2lds16(const void* g, void* l) {
  __builtin_amdgcn_global_load_lds(
      (const __attribute__((address_space(1))) unsigned int*)g,
      (__attribute__((address_space(3))) unsigned int*)l, 16, 0, 0);
}

__device__ __forceinline__ ushort8v cvt8(float4 a, float4 b) {
  ushort8v t;
  t[0] = f2bf(a.x); t[1] = f2bf(a.y); t[2] = f2bf(a.z); t[3] = f2bf(a.w);
  t[4] = f2bf(b.x); t[5] = f2bf(b.y); t[6] = f2bf(b.z); t[7] = f2bf(b.w);
  return t;
}

// ---------------------------------------------------------------------------
// groupk: bucket samples by expert; tiles of 2 same-expert samples.
// Emits order/off/cnt for the fused W2 kernel.
// ---------------------------------------------------------------------------
__global__ __launch_bounds__(256) void groupk(const int* __restrict__ cat,
                                              int* __restrict__ tiles,
                                              int* __restrict__ ntiles_out,
                                              int* __restrict__ orderG,
                                              int* __restrict__ offG,
                                              int* __restrict__ cntG) {
  __shared__ int cnt[NE], off[NE], cur[NE];
  __shared__ int order[NB];
  int tid = threadIdx.x;
  if (tid < NE) cnt[tid] = 0;
  __syncthreads();
  int e = cat[tid];
  atomicAdd(&cnt[e], 1);
  __syncthreads();
  if (tid == 0) {
    int s = 0;
    for (int i = 0; i < NE; i++) { off[i] = s; cur[i] = s; s += cnt[i]; }
  }
  __syncthreads();
  int p = atomicAdd(&cur[e], 1);
  order[p] = tid;
  __syncthreads();
  orderG[tid] = order[tid];
  if (tid < NE) { offG[tid] = off[tid]; cntG[tid] = cnt[tid]; }
  if (tid == 0) {
    int nt = 0;
    for (int i = 0; i < NE; i++) {
      for (int j = 0; j < cnt[i]; j += 2) {
        tiles[3 * nt + 0] = i;
        tiles[3 * nt + 1] = order[off[i] + j];
        tiles[3 * nt + 2] = (j + 1 < cnt[i]) ? order[off[i] + j + 1] : -1;
        nt++;
      }
    }
    *ntiles_out = nt;
  }
}

// ---------------------------------------------------------------------------
// prep: W fp32 [e][K][N=512] -> Wt bf16 [e][N][K]  (used only for W3)
// ---------------------------------------------------------------------------
__global__ __launch_bounds__(256) void prep_kernel(const float* __restrict__ W,
                                                   unsigned short* __restrict__ Wt,
                                                   int K) {
  __shared__ float S[64 * 66];
  int e = blockIdx.z;
  int nt = blockIdx.x * 64;
  int kt = blockIdx.y * 64;
  int TK = (K - kt) < 64 ? (K - kt) : 64;
  int tid = threadIdx.x;
  int units = TK * 32;  // float2 units
  for (int u = tid; u < units; u += 256) {
    int k = u >> 5, c = u & 31;
    float2 v = *(const float2*)(W + ((size_t)e * K + kt + k) * NH + nt + 2 * c);
    *(float2*)(&S[k * 66 + 2 * c]) = v;
  }
  __syncthreads();
  int csh = (TK == 64) ? 3 : 2;
  int CHm = (1 << csh) - 1;
  int wunits = 64 << csh;
  for (int u = tid; u < wunits; u += 256) {
    int n = u >> csh, c = u & CHm;
    ushort8v pk;
#pragma unroll
    for (int j = 0; j < 8; j++) pk[j] = f2bf(S[(c * 8 + j) * 66 + n]);
    *(ushort8v*)(Wt + ((size_t)e * NH + nt + n) * K + kt + c * 8) = pk;
  }
}

// ---------------------------------------------------------------------------
// w2fuse helpers
// ---------------------------------------------------------------------------
__device__ __forceinline__ void pf_w2(float2 (&pf)[8], const float* __restrict__ W2en,
                                      int k0, int tid) {
#pragma unroll
  for (int j = 0; j < 8; j++) {
    int u = j * 256 + tid;
    int kk = u >> 5, cc = u & 31;
    pf[j] = *(const float2*)(W2en + ((size_t)(k0 + kk) << 9) + cc * 2);
  }
}

__device__ __forceinline__ void pf_w1(float4 (&pfw)[2], const float* __restrict__ W1e,
                                      int k0, int tid) {
  int a = tid >> 3, p = tid & 7;
  const float* src = W1e + (size_t)a * NH + k0 + p * 8;
  pfw[0] = *(const float4*)src;
  pfw[1] = *(const float4*)(src + 4);
}

__device__ __forceinline__ void tau_stage(unsigned short* tauS,
                                          const int* __restrict__ timesteps,
                                          const int* __restrict__ orderG,
                                          int off, int c, int sg, int tid) {
  const float kLog = 0.035977893400931146f;  // ln(10000)/256
  for (int j = 0; j < 32; j++) {
    int u = j * 256 + tid;
    int s = u >> 9, k = u & 511;
    int si = sg * 16 + s;
    float t = (si < c) ? (float)timesteps[orderG[off + si]] : 0.f;
    float f = expf(-(float)(k & 255) * kLog);
    float ang = t * f;
    tauS[s * 520 + k] = f2bf((k < 256) ? sinf(ang) : cosf(ang));
  }
}

// ---------------------------------------------------------------------------
// w2fuse: fused  W12 = W1@W2a  (+ b1@W2a + b2 -> bias2)  and
//                tvec[b] = tau_b@W2b + bias2     -- per-expert, W2 read ONCE.
// grid (8, NE): block = (n0 = bx*64 cols, expert e), 256 thr = 4 waves.
// K streamed in 16 chunks of 64 rows with reg-double-buffered prefetch.
// chunks 0-7: A = W1 (bf16 MFMA, M=32);  chunks 8-15: A = tau rows (M=16/group).
// ---------------------------------------------------------------------------
__global__ __launch_bounds__(256) void w2fuse_kernel(
    const float* __restrict__ W1, const float* __restrict__ b1,
    const float* __restrict__ W2, const float* __restrict__ b2,
    const int* __restrict__ timesteps, const int* __restrict__ orderG,
    const int* __restrict__ offG, const int* __restrict__ cntG,
    unsigned short* __restrict__ Wt12, float* __restrict__ tvec) {
  __shared__ __align__(16) float S[64 * 66];            // fp32 [k][n] staging
  __shared__ __align__(16) unsigned short Bs[64 * 64];  // bf16 [n][k] XOR-swizzled
  __shared__ __align__(16) unsigned short As[32 * 64];  // bf16 [a][k] XOR-swizzled
  __shared__ __align__(16) unsigned short tauS[16 * 520];
  __shared__ __align__(16) float b1S[512];
  __shared__ __align__(16) float bias2P[64 * 8];
  __shared__ __align__(16) float bias2S[64];

  int tid = threadIdx.x;
  int e = blockIdx.y, n0 = blockIdx.x * 64;
  int w = tid >> 6, l = tid & 63;
  int lrow = l & 15, kq = l >> 4;
  int tn = tid & 63, tp = tid >> 6;  // transpose-unit indices
  int c = cntG[e], off = offG[e];

  const float* W2en = W2 + ((size_t)e << 19) + n0;
  const float* W1e = W1 + ((size_t)e << 14);

  // stage b1 row (fp32, once)
  {
    float2 v = *(const float2*)(b1 + (size_t)e * NH + tid * 2);
    *(float2*)(&b1S[tid * 2]) = v;
  }
  // tau rows for sample group 0
  tau_stage(tauS, timesteps, orderG, off, c, 0, tid);

  // prime prefetches
  float2 pf[2][8];
  float4 pfW[2][2];
  pf_w2(pf[0], W2en, 0, tid);
  pf_w1(pfW[0], W1e, 0, tid);

  f32x4 acc1[2];
  acc1[0] = (f32x4){0.f, 0.f, 0.f, 0.f};
  acc1[1] = (f32x4){0.f, 0.f, 0.f, 0.f};
  f32x4 acc2 = (f32x4){0.f, 0.f, 0.f, 0.f};
  float bacc0 = 0.f, bacc1 = 0.f;

#pragma unroll
  for (int chunk = 0; chunk < 16; chunk++) {
    const int cur = chunk & 1, nxt = cur ^ 1;
    __syncthreads();  // B1: S/Bs/As free (prev MFMA done)
    // S <- pf[cur]  (fp32 [k][66])
#pragma unroll
    for (int j = 0; j < 8; j++) {
      int u = j * 256 + tid;
      int kk = u >> 5, cc = u & 31;
      *(float2*)(&S[kk * 66 + cc * 2]) = pf[cur][j];
    }
    if (chunk < 15) pf_w2(pf[nxt], W2en, (chunk + 1) * 64, tid);
    if (chunk < 8) {
      // As <- pfW[cur] (W1 chunk, bf16, XOR chunks)
      int a = tid >> 3, p = tid & 7;
      *(ushort8v*)(&As[a * 64 + (p ^ (a & 7)) * 8]) = cvt8(pfW[cur][0], pfW[cur][1]);
      if (chunk < 7) pf_w1(pfW[nxt], W1e, (chunk + 1) * 64, tid);
    }
    __syncthreads();  // B2: S ready
    // transpose-convert S -> Bs[n][k] (XOR), + fp32 b1 dot (chunks 0-7)
#pragma unroll
    for (int i2 = 0; i2 < 2; i2++) {
      int p = tp + i2 * 4;
      ushort8v pk;
      float bsum = 0.f;
#pragma unroll
      for (int jj = 0; jj < 8; jj++) {
        float sv = S[(p * 8 + jj) * 66 + tn];
        pk[jj] = f2bf(sv);
        if (chunk < 8) bsum += sv * b1S[chunk * 64 + p * 8 + jj];
      }
      *(ushort8v*)(&Bs[tn * 64 + (p ^ (tn & 7)) * 8]) = pk;
      if (chunk < 8) { if (i2 == 0) bacc0 += bsum; else bacc1 += bsum; }
    }
    __syncthreads();  // B3: Bs/As ready
    if (chunk < 8) {
#pragma unroll
      for (int s2 = 0; s2 < 2; s2++) {
        int nrow = w * 16 + lrow;
        short8 bf = *(short8*)(&Bs[nrow * 64 + (((s2 * 4 + kq) ^ (nrow & 7))) * 8]);
#pragma unroll
        for (int mi = 0; mi < 2; mi++) {
          int ar = mi * 16 + lrow;
          short8 af = *(short8*)(&As[ar * 64 + (((s2 * 4 + kq) ^ (ar & 7))) * 8]);
          acc1[mi] = __builtin_amdgcn_mfma_f32_16x16x32_bf16(af, bf, acc1[mi], 0, 0, 0);
        }
      }
    } else {
#pragma unroll
      for (int s2 = 0; s2 < 2; s2++) {
        int nrow = w * 16 + lrow;
        short8 bf = *(short8*)(&Bs[nrow * 64 + (((s2 * 4 + kq) ^ (nrow & 7))) * 8]);
        short8 af = *(short8*)(&tauS[lrow * 520 + (chunk - 8) * 64 + s2 * 32 + kq * 8]);
        acc2 = __builtin_amdgcn_mfma_f32_16x16x32_bf16(af, bf, acc2, 0, 0, 0);
      }
    }
  }

  // ---- epilogue 1: Wt12 (LDS repack -> coalesced) + bias2 reduce ----
  unsigned short* Sb = (unsigned short*)S;  // [64 n][40] bf16 (reuse S)
#pragma unroll
  for (int mi = 0; mi < 2; mi++)
#pragma unroll
    for (int r = 0; r < 4; r++)
      Sb[(w * 16 + lrow) * 40 + mi * 16 + kq * 4 + r] = f2bf(acc1[mi][r]);
  bias2P[tn * 8 + tp] = bacc0;
  bias2P[tn * 8 + tp + 4] = bacc1;
  __syncthreads();
  if (tid < 64) {
    float s = b2[(size_t)e * NH + n0 + tid];
#pragma unroll
    for (int p2 = 0; p2 < 8; p2++) s += bias2P[tid * 8 + p2];
    bias2S[tid] = s;
  }
  {
    int n = tid >> 2, q = tid & 3;
    ushort8v v = *(ushort8v*)(&Sb[n * 40 + q * 8]);
    *(ushort8v*)(Wt12 + ((size_t)(e * NH) + n0 + n) * NA + q * 8) = v;
  }
  __syncthreads();  // bias2S visible

  // ---- epilogue 2: tvec, sample group 0 ----
  {
    float bb = bias2S[w * 16 + lrow];
#pragma unroll
    for (int r = 0; r < 4; r++) {
      int si = kq * 4 + r;
      if (si < c)
        tvec[(size_t)orderG[off + si] * NH + n0 + w * 16 + lrow] = acc2[r] + bb;
    }
  }

  // ---- extra sample groups (count_e > 16) ----
  for (int sg = 1; sg * 16 < c; sg++) {
    __syncthreads();  // prev tauS readers done
    tau_stage(tauS, timesteps, orderG, off, c, sg, tid);
    pf_w2(pf[0], W2en, 512, tid);
    f32x4 acc2b = (f32x4){0.f, 0.f, 0.f, 0.f};
#pragma unroll
    for (int chunk = 8; chunk < 16; chunk++) {
      const int cur = chunk & 1, nxt = cur ^ 1;
      __syncthreads();
#pragma unroll
      for (int j = 0; j < 8; j++) {
        int u = j * 256 + tid;
        int kk = u >> 5, cc = u & 31;
        *(float2*)(&S[kk * 66 + cc * 2]) = pf[cur][j];
      }
      if (chunk < 15) pf_w2(pf[nxt], W2en, (chunk + 1) * 64, tid);
      __syncthreads();
#pragma unroll
      for (int i2 = 0; i2 < 2; i2++) {
        int p = tp + i2 * 4;
        ushort8v pk;
#pragma unroll
        for (int jj = 0; jj < 8; jj++) pk[jj] = f2bf(S[(p * 8 + jj) * 66 + tn]);
        *(ushort8v*)(&Bs[tn * 64 + (p ^ (tn & 7)) * 8]) = pk;
      }
      __syncthreads();
#pragma unroll
      for (int s2 = 0; s2 < 2; s2++) {
        int nrow = w * 16 + lrow;
        short8 bf = *(short8*)(&Bs[nrow * 64 + (((s2 * 4 + kq) ^ (nrow & 7))) * 8]);
        short8 af = *(short8*)(&tauS[lrow * 520 + (chunk - 8) * 64 + s2 * 32 + kq * 8]);
        acc2b = __builtin_amdgcn_mfma_f32_16x16x32_bf16(af, bf, acc2b, 0, 0, 0);
      }
    }
    float bb = bias2S[w * 16 + lrow];
#pragma unroll
    for (int r = 0; r < 4; r++) {
      int si = sg * 16 + kq * 4 + r;
      if (si < c)
        tvec[(size_t)orderG[off + si] * NH + n0 + w * 16 + lrow] = acc2b[r] + bb;
    }
  }
}

// ---------------------------------------------------------------------------
// gemmh: hidden layer via FUSED weights. K=32 (one MFMA per fragment):
//   Hb[b*64+t][n] = swish( actions[b][t] @ Wt12[e] + tvec[b][n] )   (bf16 out)
// ---------------------------------------------------------------------------
__global__ __launch_bounds__(256) void gemmh_kernel(
    const float* __restrict__ actions, const unsigned short* __restrict__ Wt12,
    const float* __restrict__ tvec, const int* __restrict__ cat_ids,
    unsigned short* __restrict__ Hb) {
  __shared__ __align__(16) unsigned char smem[16384 + 5120 + 33792];
  unsigned short* Ws = (unsigned short*)smem;                   // [256][32] swizzled
  unsigned short* As = (unsigned short*)(smem + 16384);         // [64][40]
  unsigned short* Ts = (unsigned short*)(smem + 16384 + 5120);  // [64][264]

  int b = blockIdx.y, h = blockIdx.x;
  int tid = threadIdx.x;
  int e = cat_ids[b];

  {  // async stage Wt12[e][h*256 .. +256][0..32] -> Ws (chunk swizzle)
    const unsigned short* wsrc = Wt12 + ((size_t)e * NH + h * 256) * NA;
#pragma unroll
    for (int j = 0; j < 4; j++) {
      int u = j * 256 + tid;
      int n = u >> 2, p = u & 3;
      int ch = p ^ ((n >> 1) & 3);
      gl2lds16(wsrc + (size_t)n * NA + ch * 8,
               Ws + (size_t)(j * 256 + (tid & 448)) * 8);
    }
  }
  {  // stage actions (64x32 f32 -> bf16), padded stride 40
    int row = tid >> 2, seg = tid & 3;
    const float* src = actions + (size_t)(b * NT + row) * NA + seg * 8;
    float4 v0 = *(const float4*)(src);
    float4 v1 = *(const float4*)(src + 4);
    *(ushort8v*)(&As[row * 40 + seg * 8]) = cvt8(v0, v1);
  }
  __syncthreads();

  int w = tid >> 6, l = tid & 63;
  int lrow = l & 15, kq = l >> 4;
  short8 af = *(short8*)(&As[(w * 16 + lrow) * 40 + kq * 8]);
  f32x4 zero = {0.f, 0.f, 0.f, 0.f};
  f32x4 acc[16];
#pragma unroll
  for (int ni = 0; ni < 16; ni++) {
    int nn = ni * 16 + lrow;
    int p = kq ^ ((nn >> 1) & 3);
    short8 bfv = *(short8*)(&Ws[nn * 32 + p * 8]);
    acc[ni] = __builtin_amdgcn_mfma_f32_16x16x32_bf16(af, bfv, zero, 0, 0, 0);
  }
#pragma unroll
  for (int ni = 0; ni < 16; ni++) {
    int colL = ni * 16 + lrow;
    float bv = tvec[(size_t)b * NH + h * 256 + colL];  // includes bias2
#pragma unroll
    for (int r = 0; r < 4; r++) {
      int row = w * 16 + kq * 4 + r;
      float v = acc[ni][r] + bv;
      v = v / (1.0f + __expf(-v));  // swish
      Ts[row * 264 + colL] = f2bf(v);
    }
  }
  __syncthreads();
#pragma unroll
  for (int i = 0; i < 8; i++) {  // coalesced Hb rows
    int u = i * 256 + tid;
    int t = u >> 5, c4 = u & 31;
    uint4 v = *(uint4*)(&Ts[t * 264 + c4 * 8]);
    *(uint4*)(Hb + ((size_t)(b * NT + t)) * NH + h * 256 + c4 * 8) = v;
  }
}

// ---------------------------------------------------------------------------
// Grouped GEMM (verified): BM=128 x BN=64 x BK=64, 4 waves 2x2,
// global_load_lds staging, XOR-swizzled LDS, LDS-transpose epilogue.
// Instantiated only as the final layer: KTOT=512, fp32 out.
// ---------------------------------------------------------------------------
template <int KTOT, bool HASTAU, bool SWISH, bool OUT_BF16>
__global__ __launch_bounds__(256) void gemm2_kernel(
    const unsigned short* __restrict__ Xa, const unsigned short* __restrict__ Xt,
    const unsigned short* __restrict__ Wt, const float* __restrict__ bias,
    void* __restrict__ Yv, const int* __restrict__ tiles,
    const int* __restrict__ pntiles) {
  constexpr int SMEM = OUT_BF16 ? 24576 : 34816;
  __shared__ __align__(16) unsigned char smem[SMEM];
  unsigned short* As = (unsigned short*)smem;            // [128][64] swizzled
  unsigned short* Bs = (unsigned short*)(smem + 16384);  // [64][64]  swizzled

  int ti = blockIdx.y;
  if (ti >= *pntiles) return;
  int n0 = blockIdx.x * 64;
  int e = tiles[3 * ti], s0 = tiles[3 * ti + 1], s1 = tiles[3 * ti + 2];
  int s1v = (s1 < 0) ? s0 : s1;

  int tid = threadIdx.x;
  int l = tid & 63;
  int wr = (tid >> 7), wc = (tid >> 6) & 1;
  int lrow = l & 15, kq = l >> 4;

  f32x4 acc[4][2];
#pragma unroll
  for (int mi = 0; mi < 4; mi++)
#pragma unroll
    for (int ni = 0; ni < 2; ni++) acc[mi][ni] = (f32x4){0.f, 0.f, 0.f, 0.f};

  const unsigned short* wbase = Wt + ((size_t)e * NH + n0) * KTOT;

  for (int it = 0; it < KTOT / 64; it++) {
    int k0 = it * 64;
    __syncthreads();
#pragma unroll
    for (int j = 0; j < 4; j++) {
      int u = j * 256 + tid;
      int row = u >> 3, p = u & 7;
      int ch = p ^ (row & 7);
      int kk = k0 + ch * 8;
      int s = (row < 64) ? s0 : s1v;
      const unsigned short* src;
      if (HASTAU && kk >= 512)
        src = Xt + (size_t)s * NH + (kk - 512);
      else
        src = Xa + ((size_t)(s * NT + (row & 63))) * NH + kk;
      gl2lds16(src, As + (size_t)(j * 256 + (tid & 448)) * 8);
    }
#pragma unroll
    for (int j = 0; j < 2; j++) {
      int u = j * 256 + tid;
      int n = u >> 3, p = u & 7;
      int ch = p ^ (n & 7);
      gl2lds16(wbase + (size_t)n * KTOT + k0 + ch * 8,
               Bs + (size_t)(j * 256 + (tid & 448)) * 8);
    }
    __syncthreads();

    short8 afr[2][4], bfr[2][2];
#pragma unroll
    for (int s2 = 0; s2 < 2; s2++) {
#pragma unroll
      for (int mi = 0; mi < 4; mi++) {
        int row = wr * 64 + mi * 16 + lrow;
        int p = (s2 * 4 + kq) ^ (row & 7);
        afr[s2][mi] = *(short8*)(&As[row * 64 + p * 8]);
      }
#pragma unroll
      for (int ni = 0; ni < 2; ni++) {
        int n = wc * 32 + ni * 16 + lrow;
        int p = (s2 * 4 + kq) ^ (n & 7);
        bfr[s2][ni] = *(short8*)(&Bs[n * 64 + p * 8]);
      }
    }
#pragma unroll
    for (int s2 = 0; s2 < 2; s2++)
#pragma unroll
      for (int mi = 0; mi < 4; mi++)
#pragma unroll
        for (int ni = 0; ni < 2; ni++)
          acc[mi][ni] = __builtin_amdgcn_mfma_f32_16x16x32_bf16(
              afr[s2][mi], bfr[s2][ni], acc[mi][ni], 0, 0, 0);
  }
  __syncthreads();

#pragma unroll
  for (int ni = 0; ni < 2; ni++) {
    int colL = wc * 32 + ni * 16 + lrow;
    float bv = bias[(size_t)e * NH + n0 + colL];
#pragma unroll
    for (int mi = 0; mi < 4; mi++) {
#pragma unroll
      for (int r = 0; r < 4; r++) {
        int row = wr * 64 + mi * 16 + kq * 4 + r;
        float v = acc[mi][ni][r] + bv;
        if (SWISH) v = v / (1.0f + __expf(-v));
        if (OUT_BF16)
          ((unsigned short*)smem)[row * 80 + colL] = f2bf(v);
        else
          ((float*)smem)[row * 68 + colL] = v;
      }
    }
  }
  __syncthreads();
  if (OUT_BF16) {
    unsigned short* Y = (unsigned short*)Yv;
#pragma unroll
    for (int i = 0; i < 4; i++) {
      int u = i * 256 + tid;
      int row = u >> 3, c = u & 7;
      if (row >= 64 && s1 < 0) continue;
      int s = (row < 64) ? s0 : s1;
      uint4 v = *(uint4*)(&((unsigned short*)smem)[row * 80 + c * 8]);
      *(uint4*)(Y + ((size_t)(s * NT + (row & 63))) * NH + n0 + c * 8) = v;
    }
  } else {
    float* Y = (float*)Yv;
#pragma unroll
    for (int i = 0; i < 8; i++) {
      int u = i * 256 + tid;
      int row = u >> 4, c = u & 15;
      if (row >= 64 && s1 < 0) continue;
      int s = (row < 64) ? s0 : s1;
      uint4 v = *(uint4*)(&((float*)smem)[row * 68 + c * 4]);
      *(uint4*)(Y + ((size_t)(s * NT + (row & 63))) * NH + n0 + c * 4) = v;
    }
  }
}

// ---------------------------------------------------------------------------
extern "C" void kernel_launch(void* const* d_in, const int* in_sizes, int n_in,
                              void* d_out, int out_size, void* d_ws, size_t ws_size,
                              hipStream_t stream) {
  const float* actions   = (const float*)d_in[0];
  const int*   timesteps = (const int*)d_in[1];
  const int*   cat_ids   = (const int*)d_in[2];
  const float* W1 = (const float*)d_in[3];
  const float* b1 = (const float*)d_in[4];
  const float* W2 = (const float*)d_in[5];
  const float* b2 = (const float*)d_in[6];
  const float* W3 = (const float*)d_in[7];
  const float* b3 = (const float*)d_in[8];

  // ws: Hb 16MB | Wt3 16MB | Wt12 1MB | tvec 512KB | tiles+order
  unsigned short* Hb   = (unsigned short*)d_ws;
  unsigned short* Wt3  = (unsigned short*)((char*)d_ws + (size_t)16777216);
  unsigned short* Wt12 = (unsigned short*)((char*)d_ws + (size_t)33554432);
  float* tvec  = (float*)((char*)d_ws + (size_t)34603008);
  int* tiles   = (int*)((char*)d_ws + (size_t)35192832);
  int* ntiles  = tiles + 3 * MAXTILES;
  int* orderG  = ntiles + 1;
  int* offG    = orderG + NB;
  int* cntG    = offG + NE;

  groupk<<<1, 256, 0, stream>>>(cat_ids, tiles, ntiles, orderG, offG, cntG);
  w2fuse_kernel<<<dim3(8, NE), 256, 0, stream>>>(W1, b1, W2, b2, timesteps,
                                                 orderG, offG, cntG, Wt12, tvec);
  prep_kernel<<<dim3(8, 8, NE), 256, 0, stream>>>(W3, Wt3, 512);
  gemmh_kernel<<<dim3(2, NB), 256, 0, stream>>>(actions, Wt12, tvec, cat_ids, Hb);
  gemm2_kernel<512, false, false, false><<<dim3(8, MAXTILES), 256, 0, stream>>>(
      Hb, nullptr, Wt3, b3, d_out, tiles, ntiles);
}

// Round 3
// 202.572 us; speedup vs baseline: 1.7656x; 1.0494x over previous
//
#include <hip/hip_runtime.h>
#include <hip/hip_bf16.h>

// Problem: B=256, T=64, A=32, H=512, E=32
#define NB 256
#define NT 64
#define NA 32
#define NH 512
#define NE 32
#define MAXTILES 144   // max sum_e ceil(count_e/2) = 128 + 16

typedef short short8 __attribute__((ext_vector_type(8)));
typedef unsigned short ushort8v __attribute__((ext_vector_type(8)));
typedef float f32x4 __attribute__((ext_vector_type(4)));

__device__ __forceinline__ unsigned short f2bf(float f) {
  unsigned int u = __float_as_uint(f);
  u += 0x7FFFu + ((u >> 16) & 1u);   // round-to-nearest-even
  return (unsigned short)(u >> 16);
}

// async global->LDS, 16B per lane; lds dest = wave-uniform base + lane*16
__device__ __forceinline__ void gl2lds16(const void* g, void* l) {
  __builtin_amdgcn_global_load_lds(
      (const __attribute__((address_space(1))) unsigned int*)g,
      (__attribute__((address_space(3))) unsigned int*)l, 16, 0, 0);
}

__device__ __forceinline__ ushort8v cvt8(float4 a, float4 b) {
  ushort8v t;
  t[0] = f2bf(a.x); t[1] = f2bf(a.y); t[2] = f2bf(a.z); t[3] = f2bf(a.w);
  t[4] = f2bf(b.x); t[5] = f2bf(b.y); t[6] = f2bf(b.z); t[7] = f2bf(b.w);
  return t;
}

// ---------------------------------------------------------------------------
// groupk: bucket samples by expert; tiles of 2 same-expert samples.
// ---------------------------------------------------------------------------
__global__ __launch_bounds__(256) void groupk(const int* __restrict__ cat,
                                              int* __restrict__ tiles,
                                              int* __restrict__ ntiles_out,
                                              int* __restrict__ orderG,
                                              int* __restrict__ offG,
                                              int* __restrict__ cntG) {
  __shared__ int cnt[NE], off[NE], cur[NE];
  __shared__ int order[NB];
  int tid = threadIdx.x;
  if (tid < NE) cnt[tid] = 0;
  __syncthreads();
  int e = cat[tid];
  atomicAdd(&cnt[e], 1);
  __syncthreads();
  if (tid == 0) {
    int s = 0;
    for (int i = 0; i < NE; i++) { off[i] = s; cur[i] = s; s += cnt[i]; }
  }
  __syncthreads();
  int p = atomicAdd(&cur[e], 1);
  order[p] = tid;
  __syncthreads();
  orderG[tid] = order[tid];
  if (tid < NE) { offG[tid] = off[tid]; cntG[tid] = cnt[tid]; }
  if (tid == 0) {
    int nt = 0;
    for (int i = 0; i < NE; i++) {
      for (int j = 0; j < cnt[i]; j += 2) {
        tiles[3 * nt + 0] = i;
        tiles[3 * nt + 1] = order[off[i] + j];
        tiles[3 * nt + 2] = (j + 1 < cnt[i]) ? order[off[i] + j + 1] : -1;
        nt++;
      }
    }
    *ntiles_out = nt;
  }
}

// ---------------------------------------------------------------------------
// w2fuse helpers
// ---------------------------------------------------------------------------
__device__ __forceinline__ void pf_w2(float2 (&pf)[8], const float* __restrict__ W2en,
                                      int k0, int tid) {
#pragma unroll
  for (int j = 0; j < 8; j++) {
    int u = j * 256 + tid;
    int kk = u >> 5, cc = u & 31;
    pf[j] = *(const float2*)(W2en + ((size_t)(k0 + kk) << 9) + cc * 2);
  }
}

__device__ __forceinline__ void pf_w1(float4 (&pfw)[2], const float* __restrict__ W1e,
                                      int k0, int tid) {
  int a = tid >> 3, p = tid & 7;
  const float* src = W1e + (size_t)a * NH + k0 + p * 8;
  pfw[0] = *(const float4*)src;
  pfw[1] = *(const float4*)(src + 4);
}

__device__ __forceinline__ void tau_stage(unsigned short* tauS,
                                          const int* __restrict__ timesteps,
                                          const int* __restrict__ orderG,
                                          int off, int c, int sg, int tid) {
  const float kLog = 0.035977893400931146f;  // ln(10000)/256
  for (int j = 0; j < 32; j++) {
    int u = j * 256 + tid;
    int s = u >> 9, k = u & 511;
    int si = sg * 16 + s;
    float t = (si < c) ? (float)timesteps[orderG[off + si]] : 0.f;
    float f = expf(-(float)(k & 255) * kLog);
    float ang = t * f;
    tauS[s * 520 + k] = f2bf((k < 256) ? sinf(ang) : cosf(ang));
  }
}

// ---------------------------------------------------------------------------
// wp_kernel: fused launch of two INDEPENDENT roles (overlap on the device):
//   blocks [0,256):    w2fuse  — W12 = W1@W2a (+bias2), tvec = tau@W2b + bias2
//   blocks [256,2304): prep512 — W3 fp32 [e][512][512] -> Wt3 bf16 [e][n][k]
// ---------------------------------------------------------------------------
__global__ __launch_bounds__(256) void wp_kernel(
    const float* __restrict__ W1, const float* __restrict__ b1,
    const float* __restrict__ W2, const float* __restrict__ b2,
    const int* __restrict__ timesteps, const int* __restrict__ orderG,
    const int* __restrict__ offG, const int* __restrict__ cntG,
    unsigned short* __restrict__ Wt12, float* __restrict__ tvec,
    const float* __restrict__ W3, unsigned short* __restrict__ Wt3) {
  __shared__ __align__(16) unsigned char smem[50176];
  int tid = threadIdx.x;

  if (blockIdx.x >= 256) {
    // ---------------- prep512 role ----------------
    float* S = (float*)smem;  // [64][66]
    int id = blockIdx.x - 256;         // 2048 blocks
    int e = id >> 6, rem = id & 63;
    int nt = (rem & 7) * 64, kt = (rem >> 3) * 64;
#pragma unroll
    for (int j = 0; j < 8; j++) {
      int u = j * 256 + tid;
      int k = u >> 5, c = u & 31;
      float2 v = *(const float2*)(W3 + ((size_t)e * 512 + kt + k) * NH + nt + 2 * c);
      *(float2*)(&S[k * 66 + 2 * c]) = v;
    }
    __syncthreads();
#pragma unroll
    for (int j = 0; j < 2; j++) {
      int u = j * 256 + tid;
      int n = u >> 3, c = u & 7;
      ushort8v pk;
#pragma unroll
      for (int jj = 0; jj < 8; jj++) pk[jj] = f2bf(S[(c * 8 + jj) * 66 + n]);
      *(ushort8v*)(Wt3 + ((size_t)e * NH + nt + n) * 512 + kt + c * 8) = pk;
    }
    return;
  }

  // ---------------- w2fuse role ----------------
  float* S            = (float*)smem;                         // 16896 B [64][66]
  unsigned short* Bs  = (unsigned short*)(smem + 16896);      // 8192   [64][64] swz
  unsigned short* As  = (unsigned short*)(smem + 25088);      // 4096   [32][64] swz
  unsigned short* tauS= (unsigned short*)(smem + 29184);      // 16640  [16][520]
  float* b1S          = (float*)(smem + 45824);               // 2048
  float* bias2P       = (float*)(smem + 47872);               // 2048
  float* bias2S       = (float*)(smem + 49920);               // 256

  int bxx = blockIdx.x;
  int e = bxx >> 3, n0 = (bxx & 7) * 64;
  int w = tid >> 6, l = tid & 63;
  int lrow = l & 15, kq = l >> 4;
  int tn = tid & 63, tp = tid >> 6;  // transpose-unit indices
  int c = cntG[e], off = offG[e];

  const float* W2en = W2 + ((size_t)e << 19) + n0;
  const float* W1e = W1 + ((size_t)e << 14);

  {  // stage b1 row (fp32, once)
    float2 v = *(const float2*)(b1 + (size_t)e * NH + tid * 2);
    *(float2*)(&b1S[tid * 2]) = v;
  }
  tau_stage(tauS, timesteps, orderG, off, c, 0, tid);

  float2 pf[2][8];
  float4 pfW[2][2];
  pf_w2(pf[0], W2en, 0, tid);
  pf_w1(pfW[0], W1e, 0, tid);

  f32x4 acc1[2];
  acc1[0] = (f32x4){0.f, 0.f, 0.f, 0.f};
  acc1[1] = (f32x4){0.f, 0.f, 0.f, 0.f};
  f32x4 acc2 = (f32x4){0.f, 0.f, 0.f, 0.f};
  float bacc0 = 0.f, bacc1 = 0.f;

#pragma unroll
  for (int chunk = 0; chunk < 16; chunk++) {
    const int cur = chunk & 1, nxt = cur ^ 1;
    __syncthreads();  // B1: S/Bs/As free (prev MFMA done)
#pragma unroll
    for (int j = 0; j < 8; j++) {
      int u = j * 256 + tid;
      int kk = u >> 5, cc = u & 31;
      *(float2*)(&S[kk * 66 + cc * 2]) = pf[cur][j];
    }
    if (chunk < 15) pf_w2(pf[nxt], W2en, (chunk + 1) * 64, tid);
    if (chunk < 8) {
      int a = tid >> 3, p = tid & 7;
      *(ushort8v*)(&As[a * 64 + (p ^ (a & 7)) * 8]) = cvt8(pfW[cur][0], pfW[cur][1]);
      if (chunk < 7) pf_w1(pfW[nxt], W1e, (chunk + 1) * 64, tid);
    }
    __syncthreads();  // B2: S ready
#pragma unroll
    for (int i2 = 0; i2 < 2; i2++) {
      int p = tp + i2 * 4;
      ushort8v pk;
      float bsum = 0.f;
#pragma unroll
      for (int jj = 0; jj < 8; jj++) {
        float sv = S[(p * 8 + jj) * 66 + tn];
        pk[jj] = f2bf(sv);
        if (chunk < 8) bsum += sv * b1S[chunk * 64 + p * 8 + jj];
      }
      *(ushort8v*)(&Bs[tn * 64 + (p ^ (tn & 7)) * 8]) = pk;
      if (chunk < 8) { if (i2 == 0) bacc0 += bsum; else bacc1 += bsum; }
    }
    __syncthreads();  // B3: Bs/As ready
    if (chunk < 8) {
#pragma unroll
      for (int s2 = 0; s2 < 2; s2++) {
        int nrow = w * 16 + lrow;
        short8 bf = *(short8*)(&Bs[nrow * 64 + (((s2 * 4 + kq) ^ (nrow & 7))) * 8]);
#pragma unroll
        for (int mi = 0; mi < 2; mi++) {
          int ar = mi * 16 + lrow;
          short8 af = *(short8*)(&As[ar * 64 + (((s2 * 4 + kq) ^ (ar & 7))) * 8]);
          acc1[mi] = __builtin_amdgcn_mfma_f32_16x16x32_bf16(af, bf, acc1[mi], 0, 0, 0);
        }
      }
    } else {
#pragma unroll
      for (int s2 = 0; s2 < 2; s2++) {
        int nrow = w * 16 + lrow;
        short8 bf = *(short8*)(&Bs[nrow * 64 + (((s2 * 4 + kq) ^ (nrow & 7))) * 8]);
        short8 af = *(short8*)(&tauS[lrow * 520 + (chunk - 8) * 64 + s2 * 32 + kq * 8]);
        acc2 = __builtin_amdgcn_mfma_f32_16x16x32_bf16(af, bf, acc2, 0, 0, 0);
      }
    }
  }

  // ---- epilogue 1: Wt12 (LDS repack -> coalesced) + bias2 reduce ----
  unsigned short* Sb = (unsigned short*)S;  // [64 n][40] bf16 (reuse S)
#pragma unroll
  for (int mi = 0; mi < 2; mi++)
#pragma unroll
    for (int r = 0; r < 4; r++)
      Sb[(w * 16 + lrow) * 40 + mi * 16 + kq * 4 + r] = f2bf(acc1[mi][r]);
  bias2P[tn * 8 + tp] = bacc0;
  bias2P[tn * 8 + tp + 4] = bacc1;
  __syncthreads();
  if (tid < 64) {
    float s = b2[(size_t)e * NH + n0 + tid];
#pragma unroll
    for (int p2 = 0; p2 < 8; p2++) s += bias2P[tid * 8 + p2];
    bias2S[tid] = s;
  }
  {
    int n = tid >> 2, q = tid & 3;
    ushort8v v = *(ushort8v*)(&Sb[n * 40 + q * 8]);
    *(ushort8v*)(Wt12 + ((size_t)(e * NH) + n0 + n) * NA + q * 8) = v;
  }
  __syncthreads();  // bias2S visible

  // ---- epilogue 2: tvec, sample group 0 ----
  {
    float bb = bias2S[w * 16 + lrow];
#pragma unroll
    for (int r = 0; r < 4; r++) {
      int si = kq * 4 + r;
      if (si < c)
        tvec[(size_t)orderG[off + si] * NH + n0 + w * 16 + lrow] = acc2[r] + bb;
    }
  }

  // ---- extra sample groups (count_e > 16) ----
  for (int sg = 1; sg * 16 < c; sg++) {
    __syncthreads();
    tau_stage(tauS, timesteps, orderG, off, c, sg, tid);
    pf_w2(pf[0], W2en, 512, tid);
    f32x4 acc2b = (f32x4){0.f, 0.f, 0.f, 0.f};
#pragma unroll
    for (int chunk = 8; chunk < 16; chunk++) {
      const int cur = chunk & 1, nxt = cur ^ 1;
      __syncthreads();
#pragma unroll
      for (int j = 0; j < 8; j++) {
        int u = j * 256 + tid;
        int kk = u >> 5, cc = u & 31;
        *(float2*)(&S[kk * 66 + cc * 2]) = pf[cur][j];
      }
      if (chunk < 15) pf_w2(pf[nxt], W2en, (chunk + 1) * 64, tid);
      __syncthreads();
#pragma unroll
      for (int i2 = 0; i2 < 2; i2++) {
        int p = tp + i2 * 4;
        ushort8v pk;
#pragma unroll
        for (int jj = 0; jj < 8; jj++) pk[jj] = f2bf(S[(p * 8 + jj) * 66 + tn]);
        *(ushort8v*)(&Bs[tn * 64 + (p ^ (tn & 7)) * 8]) = pk;
      }
      __syncthreads();
#pragma unroll
      for (int s2 = 0; s2 < 2; s2++) {
        int nrow = w * 16 + lrow;
        short8 bf = *(short8*)(&Bs[nrow * 64 + (((s2 * 4 + kq) ^ (nrow & 7))) * 8]);
        short8 af = *(short8*)(&tauS[lrow * 520 + (chunk - 8) * 64 + s2 * 32 + kq * 8]);
        acc2b = __builtin_amdgcn_mfma_f32_16x16x32_bf16(af, bf, acc2b, 0, 0, 0);
      }
    }
    float bb = bias2S[w * 16 + lrow];
#pragma unroll
    for (int r = 0; r < 4; r++) {
      int si = sg * 16 + kq * 4 + r;
      if (si < c)
        tvec[(size_t)orderG[off + si] * NH + n0 + w * 16 + lrow] = acc2b[r] + bb;
    }
  }
}

// ---------------------------------------------------------------------------
// gemmh: hidden layer via FUSED weights. K=32 (one MFMA per fragment):
//   Hb[b*64+t][n] = swish( actions[b][t] @ Wt12[e] + tvec[b][n] )   (bf16 out)
// ---------------------------------------------------------------------------
__global__ __launch_bounds__(256) void gemmh_kernel(
    const float* __restrict__ actions, const unsigned short* __restrict__ Wt12,
    const float* __restrict__ tvec, const int* __restrict__ cat_ids,
    unsigned short* __restrict__ Hb) {
  __shared__ __align__(16) unsigned char smem[16384 + 5120 + 33792];
  unsigned short* Ws = (unsigned short*)smem;                   // [256][32] swizzled
  unsigned short* As = (unsigned short*)(smem + 16384);         // [64][40]
  unsigned short* Ts = (unsigned short*)(smem + 16384 + 5120);  // [64][264]

  int b = blockIdx.y, h = blockIdx.x;
  int tid = threadIdx.x;
  int e = cat_ids[b];

  {  // async stage Wt12[e][h*256 .. +256][0..32] -> Ws (chunk swizzle)
    const unsigned short* wsrc = Wt12 + ((size_t)e * NH + h * 256) * NA;
#pragma unroll
    for (int j = 0; j < 4; j++) {
      int u = j * 256 + tid;
      int n = u >> 2, p = u & 3;
      int ch = p ^ ((n >> 1) & 3);
      gl2lds16(wsrc + (size_t)n * NA + ch * 8,
               Ws + (size_t)(j * 256 + (tid & 448)) * 8);
    }
  }
  {  // stage actions (64x32 f32 -> bf16), padded stride 40
    int row = tid >> 2, seg = tid & 3;
    const float* src = actions + (size_t)(b * NT + row) * NA + seg * 8;
    float4 v0 = *(const float4*)(src);
    float4 v1 = *(const float4*)(src + 4);
    *(ushort8v*)(&As[row * 40 + seg * 8]) = cvt8(v0, v1);
  }
  __syncthreads();

  int w = tid >> 6, l = tid & 63;
  int lrow = l & 15, kq = l >> 4;
  short8 af = *(short8*)(&As[(w * 16 + lrow) * 40 + kq * 8]);
  f32x4 zero = {0.f, 0.f, 0.f, 0.f};
  f32x4 acc[16];
#pragma unroll
  for (int ni = 0; ni < 16; ni++) {
    int nn = ni * 16 + lrow;
    int p = kq ^ ((nn >> 1) & 3);
    short8 bfv = *(short8*)(&Ws[nn * 32 + p * 8]);
    acc[ni] = __builtin_amdgcn_mfma_f32_16x16x32_bf16(af, bfv, zero, 0, 0, 0);
  }
#pragma unroll
  for (int ni = 0; ni < 16; ni++) {
    int colL = ni * 16 + lrow;
    float bv = tvec[(size_t)b * NH + h * 256 + colL];  // includes bias2
#pragma unroll
    for (int r = 0; r < 4; r++) {
      int row = w * 16 + kq * 4 + r;
      float v = acc[ni][r] + bv;
      v = v / (1.0f + __expf(-v));  // swish
      Ts[row * 264 + colL] = f2bf(v);
    }
  }
  __syncthreads();
#pragma unroll
  for (int i = 0; i < 8; i++) {  // coalesced Hb rows
    int u = i * 256 + tid;
    int t = u >> 5, c4 = u & 31;
    uint4 v = *(uint4*)(&Ts[t * 264 + c4 * 8]);
    *(uint4*)(Hb + ((size_t)(b * NT + t)) * NH + h * 256 + c4 * 8) = v;
  }
}

// ---------------------------------------------------------------------------
// Grouped GEMM, 2-phase double-buffered pipeline (T3/T4): stage tile t+2 while
// computing tile t; counted vmcnt(6) + raw s_barrier — no full drains in loop.
// BM=128 x BN=64 x BK=64, 4 waves 2x2, XOR-swizzled LDS, transpose epilogue.
// ---------------------------------------------------------------------------
template <int KTOT, bool HASTAU, bool SWISH, bool OUT_BF16>
__global__ __launch_bounds__(256) void gemm2_kernel(
    const unsigned short* __restrict__ Xa, const unsigned short* __restrict__ Xt,
    const unsigned short* __restrict__ Wt, const float* __restrict__ bias,
    void* __restrict__ Yv, const int* __restrict__ tiles,
    const int* __restrict__ pntiles) {
  __shared__ __align__(16) unsigned char smem[49152];  // 2 x (As 16K + Bs 8K)

  int ti = blockIdx.y;
  if (ti >= *pntiles) return;
  int n0 = blockIdx.x * 64;
  int e = tiles[3 * ti], s0 = tiles[3 * ti + 1], s1 = tiles[3 * ti + 2];
  int s1v = (s1 < 0) ? s0 : s1;

  int tid = threadIdx.x;
  int l = tid & 63;
  int wr = (tid >> 7), wc = (tid >> 6) & 1;
  int lrow = l & 15, kq = l >> 4;

  const unsigned short* wbase = Wt + ((size_t)e * NH + n0) * KTOT;
  constexpr int NIT = KTOT / 64;

  // stage K-tile `it` into buffer `buf` (6 gl2lds issues per wave)
  auto stage = [&](int it, int buf) {
    unsigned short* As = (unsigned short*)(smem + buf * 24576);
    unsigned short* Bs = (unsigned short*)(smem + buf * 24576 + 16384);
    int k0 = it * 64;
#pragma unroll
    for (int j = 0; j < 4; j++) {
      int u = j * 256 + tid;
      int row = u >> 3, p = u & 7;
      int ch = p ^ (row & 7);
      int kk = k0 + ch * 8;
      int s = (row < 64) ? s0 : s1v;
      const unsigned short* src;
      if (HASTAU && kk >= 512)
        src = Xt + (size_t)s * NH + (kk - 512);
      else
        src = Xa + ((size_t)(s * NT + (row & 63))) * NH + kk;
      gl2lds16(src, As + (size_t)(j * 256 + (tid & 448)) * 8);
    }
#pragma unroll
    for (int j = 0; j < 2; j++) {
      int u = j * 256 + tid;
      int n = u >> 3, p = u & 7;
      int ch = p ^ (n & 7);
      gl2lds16(wbase + (size_t)n * KTOT + k0 + ch * 8,
               Bs + (size_t)(j * 256 + (tid & 448)) * 8);
    }
  };

  f32x4 acc[4][2];
#pragma unroll
  for (int mi = 0; mi < 4; mi++)
#pragma unroll
    for (int ni = 0; ni < 2; ni++) acc[mi][ni] = (f32x4){0.f, 0.f, 0.f, 0.f};

  stage(0, 0);
  stage(1, 1);

  for (int t = 0; t < NIT; t++) {
    int cur = t & 1;
    unsigned short* As = (unsigned short*)(smem + cur * 24576);
    unsigned short* Bs = (unsigned short*)(smem + cur * 24576 + 16384);

    // tile t's 6 loads are the oldest; keep tile t+1's (and later) in flight
    if (t + 1 < NIT) {
      asm volatile("s_waitcnt vmcnt(6)" ::: "memory");
    } else {
      asm volatile("s_waitcnt vmcnt(0)" ::: "memory");
    }
    __builtin_amdgcn_sched_barrier(0);
    __builtin_amdgcn_s_barrier();   // all waves' tile-t stores landed
    __builtin_amdgcn_sched_barrier(0);

    short8 afr[2][4], bfr[2][2];
#pragma unroll
    for (int s2 = 0; s2 < 2; s2++) {
#pragma unroll
      for (int mi = 0; mi < 4; mi++) {
        int row = wr * 64 + mi * 16 + lrow;
        int p = (s2 * 4 + kq) ^ (row & 7);
        afr[s2][mi] = *(short8*)(&As[row * 64 + p * 8]);
      }
#pragma unroll
      for (int ni = 0; ni < 2; ni++) {
        int n = wc * 32 + ni * 16 + lrow;
        int p = (s2 * 4 + kq) ^ (n & 7);
        bfr[s2][ni] = *(short8*)(&Bs[n * 64 + p * 8]);
      }
    }
    asm volatile("s_waitcnt lgkmcnt(0)" ::: "memory");  // frags in regs
    __builtin_amdgcn_sched_barrier(0);
    __builtin_amdgcn_s_barrier();   // all waves done READING buf[cur]
    __builtin_amdgcn_sched_barrier(0);

    if (t + 2 < NIT) stage(t + 2, cur);  // overwrite cur slot; overlaps MFMA

#pragma unroll
    for (int s2 = 0; s2 < 2; s2++)
#pragma unroll
      for (int mi = 0; mi < 4; mi++)
#pragma unroll
        for (int ni = 0; ni < 2; ni++)
          acc[mi][ni] = __builtin_amdgcn_mfma_f32_16x16x32_bf16(
              afr[s2][mi], bfr[s2][ni], acc[mi][ni], 0, 0, 0);
  }
  __syncthreads();

  // epilogue: bias(+swish) -> LDS transpose -> coalesced stores
#pragma unroll
  for (int ni = 0; ni < 2; ni++) {
    int colL = wc * 32 + ni * 16 + lrow;
    float bv = bias[(size_t)e * NH + n0 + colL];
#pragma unroll
    for (int mi = 0; mi < 4; mi++) {
#pragma unroll
      for (int r = 0; r < 4; r++) {
        int row = wr * 64 + mi * 16 + kq * 4 + r;
        float v = acc[mi][ni][r] + bv;
        if (SWISH) v = v / (1.0f + __expf(-v));
        if (OUT_BF16)
          ((unsigned short*)smem)[row * 80 + colL] = f2bf(v);
        else
          ((float*)smem)[row * 68 + colL] = v;
      }
    }
  }
  __syncthreads();
  if (OUT_BF16) {
    unsigned short* Y = (unsigned short*)Yv;
#pragma unroll
    for (int i = 0; i < 4; i++) {
      int u = i * 256 + tid;
      int row = u >> 3, c = u & 7;
      if (row >= 64 && s1 < 0) continue;
      int s = (row < 64) ? s0 : s1;
      uint4 v = *(uint4*)(&((unsigned short*)smem)[row * 80 + c * 8]);
      *(uint4*)(Y + ((size_t)(s * NT + (row & 63))) * NH + n0 + c * 8) = v;
    }
  } else {
    float* Y = (float*)Yv;
#pragma unroll
    for (int i = 0; i < 8; i++) {
      int u = i * 256 + tid;
      int row = u >> 4, c = u & 15;
      if (row >= 64 && s1 < 0) continue;
      int s = (row < 64) ? s0 : s1;
      uint4 v = *(uint4*)(&((float*)smem)[row * 68 + c * 4]);
      *(uint4*)(Y + ((size_t)(s * NT + (row & 63))) * NH + n0 + c * 4) = v;
    }
  }
}

// ---------------------------------------------------------------------------
extern "C" void kernel_launch(void* const* d_in, const int* in_sizes, int n_in,
                              void* d_out, int out_size, void* d_ws, size_t ws_size,
                              hipStream_t stream) {
  const float* actions   = (const float*)d_in[0];
  const int*   timesteps = (const int*)d_in[1];
  const int*   cat_ids   = (const int*)d_in[2];
  const float* W1 = (const float*)d_in[3];
  const float* b1 = (const float*)d_in[4];
  const float* W2 = (const float*)d_in[5];
  const float* b2 = (const float*)d_in[6];
  const float* W3 = (const float*)d_in[7];
  const float* b3 = (const float*)d_in[8];

  // ws: Hb 16MB | Wt3 16MB | Wt12 1MB | tvec 512KB | tiles+order
  unsigned short* Hb   = (unsigned short*)d_ws;
  unsigned short* Wt3  = (unsigned short*)((char*)d_ws + (size_t)16777216);
  unsigned short* Wt12 = (unsigned short*)((char*)d_ws + (size_t)33554432);
  float* tvec  = (float*)((char*)d_ws + (size_t)34603008);
  int* tiles   = (int*)((char*)d_ws + (size_t)35192832);
  int* ntiles  = tiles + 3 * MAXTILES;
  int* orderG  = ntiles + 1;
  int* offG    = orderG + NB;
  int* cntG    = offG + NE;

  groupk<<<1, 256, 0, stream>>>(cat_ids, tiles, ntiles, orderG, offG, cntG);
  wp_kernel<<<2304, 256, 0, stream>>>(W1, b1, W2, b2, timesteps, orderG, offG,
                                      cntG, Wt12, tvec, W3, Wt3);
  gemmh_kernel<<<dim3(2, NB), 256, 0, stream>>>(actions, Wt12, tvec, cat_ids, Hb);
  gemm2_kernel<512, false, false, false><<<dim3(8, MAXTILES), 256, 0, stream>>>(
      Hb, nullptr, Wt3, b3, d_out, tiles, ntiles);
}

// Round 4
// 195.437 us; speedup vs baseline: 1.8300x; 1.0365x over previous
//
#include <hip/hip_runtime.h>
#include <hip/hip_bf16.h>

// Problem: B=256, T=64, A=32, H=512, E=32
#define NB 256
#define NT 64
#define NA 32
#define NH 512
#define NE 32
#define MAXTILES 144   // max sum_e ceil(count_e/2) = 128 + 16

typedef short short8 __attribute__((ext_vector_type(8)));
typedef unsigned short ushort8v __attribute__((ext_vector_type(8)));
typedef float f32x4 __attribute__((ext_vector_type(4)));

__device__ __forceinline__ unsigned short f2bf(float f) {
  unsigned int u = __float_as_uint(f);
  u += 0x7FFFu + ((u >> 16) & 1u);   // round-to-nearest-even
  return (unsigned short)(u >> 16);
}

// async global->LDS, 16B per lane; lds dest = wave-uniform base + lane*16
__device__ __forceinline__ void gl2lds16(const void* g, void* l) {
  __builtin_amdgcn_global_load_lds(
      (const __attribute__((address_space(1))) unsigned int*)g,
      (__attribute__((address_space(3))) unsigned int*)l, 16, 0, 0);
}

__device__ __forceinline__ ushort8v cvt8(float4 a, float4 b) {
  ushort8v t;
  t[0] = f2bf(a.x); t[1] = f2bf(a.y); t[2] = f2bf(a.z); t[3] = f2bf(a.w);
  t[4] = f2bf(b.x); t[5] = f2bf(b.y); t[6] = f2bf(b.z); t[7] = f2bf(b.w);
  return t;
}

// prefetch helpers (reg double-buffered W2 column-slice stream)
__device__ __forceinline__ void pf_w2(float2 (&pf)[8], const float* __restrict__ W2en,
                                      int k0, int tid) {
#pragma unroll
  for (int j = 0; j < 8; j++) {
    int u = j * 256 + tid;
    int kk = u >> 5, cc = u & 31;
    pf[j] = *(const float2*)(W2en + ((size_t)(k0 + kk) << 9) + cc * 2);
  }
}

__device__ __forceinline__ void pf_w1(float4 (&pfw)[2], const float* __restrict__ W1e,
                                      int k0, int tid) {
  int a = tid >> 3, p = tid & 7;
  const float* src = W1e + (size_t)a * NH + k0 + p * 8;
  pfw[0] = *(const float4*)src;
  pfw[1] = *(const float4*)(src + 4);
}

// ---------------------------------------------------------------------------
// wp_kernel: four INDEPENDENT roles in one launch (device-level overlap):
//   blocks [0,256):     W12-role  — W12 = W1@W2a (bf16 out) + bias2 = b1@W2a+b2
//   blocks [256,512):   tvec-role — tvec[b] = tau_b@W2b (raw, bias2 added later)
//                       (self-groups samples from cat_ids; no groupk dependency)
//   blocks [512,2560):  prep-role — W3 fp32 -> Wt3 bf16 [e][n][k]
//   block  2560:        groupk-role — tiles for the grouped GEMM
// ---------------------------------------------------------------------------
__global__ __launch_bounds__(256) void wp_kernel(
    const float* __restrict__ W1, const float* __restrict__ b1,
    const float* __restrict__ W2, const float* __restrict__ b2,
    const float* __restrict__ W3, const int* __restrict__ timesteps,
    const int* __restrict__ cat, unsigned short* __restrict__ Wt12,
    float* __restrict__ bias2G, float* __restrict__ tvec,
    unsigned short* __restrict__ Wt3, int* __restrict__ tiles,
    int* __restrict__ ntiles_out) {
  __shared__ __align__(16) unsigned char smem[43008];
  int tid = threadIdx.x;
  int bx = blockIdx.x;

  if (bx >= 512 && bx < 2560) {
    // ---------------- prep role (W3 transpose+convert) ----------------
    float* S = (float*)smem;  // [64][66]
    int id = bx - 512;        // 2048 blocks
    int e = id >> 6, rem = id & 63;
    int nt = (rem & 7) * 64, kt = (rem >> 3) * 64;
#pragma unroll
    for (int j = 0; j < 8; j++) {
      int u = j * 256 + tid;
      int k = u >> 5, c = u & 31;
      float2 v = *(const float2*)(W3 + ((size_t)e * 512 + kt + k) * NH + nt + 2 * c);
      *(float2*)(&S[k * 66 + 2 * c]) = v;
    }
    __syncthreads();
#pragma unroll
    for (int j = 0; j < 2; j++) {
      int u = j * 256 + tid;
      int n = u >> 3, c = u & 7;
      ushort8v pk;
#pragma unroll
      for (int jj = 0; jj < 8; jj++) pk[jj] = f2bf(S[(c * 8 + jj) * 66 + n]);
      *(ushort8v*)(Wt3 + ((size_t)e * NH + nt + n) * 512 + kt + c * 8) = pk;
    }
    return;
  }

  if (bx == 2560) {
    // ---------------- groupk role ----------------
    int* cnt = (int*)smem;
    int* off = cnt + 32;
    int* cur = off + 32;
    int* order = cur + 32;
    if (tid < NE) cnt[tid] = 0;
    __syncthreads();
    int e = cat[tid];
    atomicAdd(&cnt[e], 1);
    __syncthreads();
    if (tid == 0) {
      int s = 0;
      for (int i = 0; i < NE; i++) { off[i] = s; cur[i] = s; s += cnt[i]; }
    }
    __syncthreads();
    int p = atomicAdd(&cur[e], 1);
    order[p] = tid;
    __syncthreads();
    if (tid == 0) {
      int nt = 0;
      for (int i = 0; i < NE; i++) {
        for (int j = 0; j < cnt[i]; j += 2) {
          tiles[3 * nt + 0] = i;
          tiles[3 * nt + 1] = order[off[i] + j];
          tiles[3 * nt + 2] = (j + 1 < cnt[i]) ? order[off[i] + j + 1] : -1;
          nt++;
        }
      }
      *ntiles_out = nt;
    }
    return;
  }

  int w = tid >> 6, l = tid & 63;
  int lrow = l & 15, kq = l >> 4;
  int tn = tid & 63, tp = tid >> 6;  // transpose-unit indices

  if (bx < 256) {
    // ---------------- W12 role ----------------
    float* S            = (float*)smem;                     // 16896 [64][66]
    unsigned short* Bs  = (unsigned short*)(smem + 16896);  // 8192  [64][64] swz
    unsigned short* As  = (unsigned short*)(smem + 25088);  // 4096  [32][64] swz
    float* b1S          = (float*)(smem + 29184);           // 2048
    float* bias2P       = (float*)(smem + 31232);           // 2048

    int e = bx >> 3, n0 = (bx & 7) * 64;
    const float* W2en = W2 + ((size_t)e << 19) + n0;   // W2a rows 0..511
    const float* W1e = W1 + ((size_t)e << 14);

    {  // stage b1 row (fp32, once)
      float2 v = *(const float2*)(b1 + (size_t)e * NH + tid * 2);
      *(float2*)(&b1S[tid * 2]) = v;
    }

    float2 pf[2][8];
    float4 pfW[2][2];
    pf_w2(pf[0], W2en, 0, tid);
    pf_w1(pfW[0], W1e, 0, tid);

    f32x4 acc1[2];
    acc1[0] = (f32x4){0.f, 0.f, 0.f, 0.f};
    acc1[1] = (f32x4){0.f, 0.f, 0.f, 0.f};
    float bacc0 = 0.f, bacc1 = 0.f;

#pragma unroll
    for (int chunk = 0; chunk < 8; chunk++) {
      const int cur = chunk & 1, nxt = cur ^ 1;
      __syncthreads();  // B1: S/Bs/As free (prev MFMA done)
#pragma unroll
      for (int j = 0; j < 8; j++) {
        int u = j * 256 + tid;
        int kk = u >> 5, cc = u & 31;
        *(float2*)(&S[kk * 66 + cc * 2]) = pf[cur][j];
      }
      {  // As <- W1 chunk (bf16, XOR chunks)
        int a = tid >> 3, p = tid & 7;
        *(ushort8v*)(&As[a * 64 + (p ^ (a & 7)) * 8]) = cvt8(pfW[cur][0], pfW[cur][1]);
      }
      if (chunk < 7) {
        pf_w2(pf[nxt], W2en, (chunk + 1) * 64, tid);
        pf_w1(pfW[nxt], W1e, (chunk + 1) * 64, tid);
      }
      __syncthreads();  // B2: S ready
#pragma unroll
      for (int i2 = 0; i2 < 2; i2++) {
        int p = tp + i2 * 4;
        ushort8v pk;
        float bsum = 0.f;
#pragma unroll
        for (int jj = 0; jj < 8; jj++) {
          float sv = S[(p * 8 + jj) * 66 + tn];
          pk[jj] = f2bf(sv);
          bsum += sv * b1S[chunk * 64 + p * 8 + jj];
        }
        *(ushort8v*)(&Bs[tn * 64 + (p ^ (tn & 7)) * 8]) = pk;
        if (i2 == 0) bacc0 += bsum; else bacc1 += bsum;
      }
      __syncthreads();  // B3: Bs/As ready
#pragma unroll
      for (int s2 = 0; s2 < 2; s2++) {
        int nrow = w * 16 + lrow;
        short8 bf = *(short8*)(&Bs[nrow * 64 + (((s2 * 4 + kq) ^ (nrow & 7))) * 8]);
#pragma unroll
        for (int mi = 0; mi < 2; mi++) {
          int ar = mi * 16 + lrow;
          short8 af = *(short8*)(&As[ar * 64 + (((s2 * 4 + kq) ^ (ar & 7))) * 8]);
          acc1[mi] = __builtin_amdgcn_mfma_f32_16x16x32_bf16(af, bf, acc1[mi], 0, 0, 0);
        }
      }
    }

    // epilogue: Wt12 (LDS repack -> coalesced) + bias2 reduce
    unsigned short* Sb = (unsigned short*)S;  // [64 n][40] bf16 (reuse S)
#pragma unroll
    for (int mi = 0; mi < 2; mi++)
#pragma unroll
      for (int r = 0; r < 4; r++)
        Sb[(w * 16 + lrow) * 40 + mi * 16 + kq * 4 + r] = f2bf(acc1[mi][r]);
    bias2P[tn * 8 + tp] = bacc0;
    bias2P[tn * 8 + tp + 4] = bacc1;
    __syncthreads();
    if (tid < 64) {
      float s = b2[(size_t)e * NH + n0 + tid];
#pragma unroll
      for (int p2 = 0; p2 < 8; p2++) s += bias2P[tid * 8 + p2];
      bias2G[(size_t)e * NH + n0 + tid] = s;
    }
    {
      int n = tid >> 2, q = tid & 3;
      ushort8v v = *(ushort8v*)(&Sb[n * 40 + q * 8]);
      *(ushort8v*)(Wt12 + ((size_t)(e * NH) + n0 + n) * NA + q * 8) = v;
    }
    return;
  }

  // ---------------- tvec role ----------------
  {
    float* S            = (float*)smem;                     // 16896 [64][66]
    unsigned short* Bs  = (unsigned short*)(smem + 16896);  // 8192  [64][64] swz
    unsigned short* tauS= (unsigned short*)(smem + 25088);  // 16640 [16][520]
    int* list           = (int*)(smem + 41728);             // 1024
    int* pcnt           = (int*)(smem + 42752);

    int id = bx - 256;
    int e = id >> 3, n0 = (id & 7) * 64;
    const float* W2bn = W2 + ((size_t)e << 19) + ((size_t)512 << 9) + n0;  // W2b

    if (tid == 0) *pcnt = 0;
    __syncthreads();
    {
      int ce = cat[tid];  // tid in [0,256) == NB
      if (ce == e) { int p = atomicAdd(pcnt, 1); list[p] = tid; }
    }
    __syncthreads();
    int c = *pcnt;
    if (c == 0) return;

    const float kLog = 0.035977893400931146f;  // ln(10000)/256
    float2 pf[2][8];

    for (int sg = 0; sg * 16 < c; sg++) {
      if (sg > 0) __syncthreads();  // prev tauS readers done
      // stage tau rows for samples sg*16..sg*16+15
      for (int j = 0; j < 32; j++) {
        int u = j * 256 + tid;
        int s = u >> 9, k = u & 511;
        int si = sg * 16 + s;
        float t = (si < c) ? (float)timesteps[list[si]] : 0.f;
        float f = expf(-(float)(k & 255) * kLog);
        float ang = t * f;
        tauS[s * 520 + k] = f2bf((k < 256) ? sinf(ang) : cosf(ang));
      }
      pf_w2(pf[0], W2bn, 0, tid);
      f32x4 acc2 = (f32x4){0.f, 0.f, 0.f, 0.f};
#pragma unroll
      for (int chunk = 0; chunk < 8; chunk++) {
        const int cur = chunk & 1, nxt = cur ^ 1;
        __syncthreads();  // B1: S/Bs free
#pragma unroll
        for (int j = 0; j < 8; j++) {
          int u = j * 256 + tid;
          int kk = u >> 5, cc = u & 31;
          *(float2*)(&S[kk * 66 + cc * 2]) = pf[cur][j];
        }
        if (chunk < 7) pf_w2(pf[nxt], W2bn, (chunk + 1) * 64, tid);
        __syncthreads();  // B2: S ready
#pragma unroll
        for (int i2 = 0; i2 < 2; i2++) {
          int p = tp + i2 * 4;
          ushort8v pk;
#pragma unroll
          for (int jj = 0; jj < 8; jj++) pk[jj] = f2bf(S[(p * 8 + jj) * 66 + tn]);
          *(ushort8v*)(&Bs[tn * 64 + (p ^ (tn & 7)) * 8]) = pk;
        }
        __syncthreads();  // B3: Bs ready
#pragma unroll
        for (int s2 = 0; s2 < 2; s2++) {
          int nrow = w * 16 + lrow;
          short8 bf = *(short8*)(&Bs[nrow * 64 + (((s2 * 4 + kq) ^ (nrow & 7))) * 8]);
          short8 af = *(short8*)(&tauS[lrow * 520 + chunk * 64 + s2 * 32 + kq * 8]);
          acc2 = __builtin_amdgcn_mfma_f32_16x16x32_bf16(af, bf, acc2, 0, 0, 0);
        }
      }
#pragma unroll
      for (int r = 0; r < 4; r++) {
        int si = sg * 16 + kq * 4 + r;
        if (si < c)
          tvec[(size_t)list[si] * NH + n0 + w * 16 + lrow] = acc2[r];
      }
    }
  }
}

// ---------------------------------------------------------------------------
// gemmh: hidden layer via FUSED weights. K=32 (one MFMA per fragment):
//   Hb[b*64+t][n] = swish( actions[b][t] @ Wt12[e] + tvec[b][n] + bias2[e][n] )
// ---------------------------------------------------------------------------
__global__ __launch_bounds__(256) void gemmh_kernel(
    const float* __restrict__ actions, const unsigned short* __restrict__ Wt12,
    const float* __restrict__ tvec, const float* __restrict__ bias2,
    const int* __restrict__ cat_ids, unsigned short* __restrict__ Hb) {
  __shared__ __align__(16) unsigned char smem[16384 + 5120 + 33792];
  unsigned short* Ws = (unsigned short*)smem;                   // [256][32] swizzled
  unsigned short* As = (unsigned short*)(smem + 16384);         // [64][40]
  unsigned short* Ts = (unsigned short*)(smem + 16384 + 5120);  // [64][264]

  int b = blockIdx.y, h = blockIdx.x;
  int tid = threadIdx.x;
  int e = cat_ids[b];

  {  // async stage Wt12[e][h*256 .. +256][0..32] -> Ws (chunk swizzle)
    const unsigned short* wsrc = Wt12 + ((size_t)e * NH + h * 256) * NA;
#pragma unroll
    for (int j = 0; j < 4; j++) {
      int u = j * 256 + tid;
      int n = u >> 2, p = u & 3;
      int ch = p ^ ((n >> 1) & 3);
      gl2lds16(wsrc + (size_t)n * NA + ch * 8,
               Ws + (size_t)(j * 256 + (tid & 448)) * 8);
    }
  }
  {  // stage actions (64x32 f32 -> bf16), padded stride 40
    int row = tid >> 2, seg = tid & 3;
    const float* src = actions + (size_t)(b * NT + row) * NA + seg * 8;
    float4 v0 = *(const float4*)(src);
    float4 v1 = *(const float4*)(src + 4);
    *(ushort8v*)(&As[row * 40 + seg * 8]) = cvt8(v0, v1);
  }
  __syncthreads();

  int w = tid >> 6, l = tid & 63;
  int lrow = l & 15, kq = l >> 4;
  short8 af = *(short8*)(&As[(w * 16 + lrow) * 40 + kq * 8]);
  f32x4 zero = {0.f, 0.f, 0.f, 0.f};
  f32x4 acc[16];
#pragma unroll
  for (int ni = 0; ni < 16; ni++) {
    int nn = ni * 16 + lrow;
    int p = kq ^ ((nn >> 1) & 3);
    short8 bfv = *(short8*)(&Ws[nn * 32 + p * 8]);
    acc[ni] = __builtin_amdgcn_mfma_f32_16x16x32_bf16(af, bfv, zero, 0, 0, 0);
  }
#pragma unroll
  for (int ni = 0; ni < 16; ni++) {
    int colL = ni * 16 + lrow;
    float bv = tvec[(size_t)b * NH + h * 256 + colL] +
               bias2[(size_t)e * NH + h * 256 + colL];
#pragma unroll
    for (int r = 0; r < 4; r++) {
      int row = w * 16 + kq * 4 + r;
      float v = acc[ni][r] + bv;
      v = v / (1.0f + __expf(-v));  // swish
      Ts[row * 264 + colL] = f2bf(v);
    }
  }
  __syncthreads();
#pragma unroll
  for (int i = 0; i < 8; i++) {  // coalesced Hb rows
    int u = i * 256 + tid;
    int t = u >> 5, c4 = u & 31;
    uint4 v = *(uint4*)(&Ts[t * 264 + c4 * 8]);
    *(uint4*)(Hb + ((size_t)(b * NT + t)) * NH + h * 256 + c4 * 8) = v;
  }
}

// ---------------------------------------------------------------------------
// Grouped GEMM, 2-phase double-buffered pipeline (T3/T4): stage tile t+2 while
// computing tile t; counted vmcnt(6) + raw s_barrier — no full drains in loop.
// BM=128 x BN=64 x BK=64, 4 waves 2x2, XOR-swizzled LDS, transpose epilogue.
// ---------------------------------------------------------------------------
template <int KTOT, bool HASTAU, bool SWISH, bool OUT_BF16>
__global__ __launch_bounds__(256) void gemm2_kernel(
    const unsigned short* __restrict__ Xa, const unsigned short* __restrict__ Xt,
    const unsigned short* __restrict__ Wt, const float* __restrict__ bias,
    void* __restrict__ Yv, const int* __restrict__ tiles,
    const int* __restrict__ pntiles) {
  __shared__ __align__(16) unsigned char smem[49152];  // 2 x (As 16K + Bs 8K)

  int ti = blockIdx.y;
  if (ti >= *pntiles) return;
  int n0 = blockIdx.x * 64;
  int e = tiles[3 * ti], s0 = tiles[3 * ti + 1], s1 = tiles[3 * ti + 2];
  int s1v = (s1 < 0) ? s0 : s1;

  int tid = threadIdx.x;
  int l = tid & 63;
  int wr = (tid >> 7), wc = (tid >> 6) & 1;
  int lrow = l & 15, kq = l >> 4;

  const unsigned short* wbase = Wt + ((size_t)e * NH + n0) * KTOT;
  constexpr int NIT = KTOT / 64;

  // stage K-tile `it` into buffer `buf` (6 gl2lds issues per thread)
  auto stage = [&](int it, int buf) {
    unsigned short* As = (unsigned short*)(smem + buf * 24576);
    unsigned short* Bs = (unsigned short*)(smem + buf * 24576 + 16384);
    int k0 = it * 64;
#pragma unroll
    for (int j = 0; j < 4; j++) {
      int u = j * 256 + tid;
      int row = u >> 3, p = u & 7;
      int ch = p ^ (row & 7);
      int kk = k0 + ch * 8;
      int s = (row < 64) ? s0 : s1v;
      const unsigned short* src;
      if (HASTAU && kk >= 512)
        src = Xt + (size_t)s * NH + (kk - 512);
      else
        src = Xa + ((size_t)(s * NT + (row & 63))) * NH + kk;
      gl2lds16(src, As + (size_t)(j * 256 + (tid & 448)) * 8);
    }
#pragma unroll
    for (int j = 0; j < 2; j++) {
      int u = j * 256 + tid;
      int n = u >> 3, p = u & 7;
      int ch = p ^ (n & 7);
      gl2lds16(wbase + (size_t)n * KTOT + k0 + ch * 8,
               Bs + (size_t)(j * 256 + (tid & 448)) * 8);
    }
  };

  f32x4 acc[4][2];
#pragma unroll
  for (int mi = 0; mi < 4; mi++)
#pragma unroll
    for (int ni = 0; ni < 2; ni++) acc[mi][ni] = (f32x4){0.f, 0.f, 0.f, 0.f};

  stage(0, 0);
  stage(1, 1);

  for (int t = 0; t < NIT; t++) {
    int cur = t & 1;
    unsigned short* As = (unsigned short*)(smem + cur * 24576);
    unsigned short* Bs = (unsigned short*)(smem + cur * 24576 + 16384);

    // tile t's 6 loads are the oldest; keep tile t+1's in flight
    if (t + 1 < NIT) {
      asm volatile("s_waitcnt vmcnt(6)" ::: "memory");
    } else {
      asm volatile("s_waitcnt vmcnt(0)" ::: "memory");
    }
    __builtin_amdgcn_sched_barrier(0);
    __builtin_amdgcn_s_barrier();   // all waves' tile-t stores landed
    __builtin_amdgcn_sched_barrier(0);

    short8 afr[2][4], bfr[2][2];
#pragma unroll
    for (int s2 = 0; s2 < 2; s2++) {
#pragma unroll
      for (int mi = 0; mi < 4; mi++) {
        int row = wr * 64 + mi * 16 + lrow;
        int p = (s2 * 4 + kq) ^ (row & 7);
        afr[s2][mi] = *(short8*)(&As[row * 64 + p * 8]);
      }
#pragma unroll
      for (int ni = 0; ni < 2; ni++) {
        int n = wc * 32 + ni * 16 + lrow;
        int p = (s2 * 4 + kq) ^ (n & 7);
        bfr[s2][ni] = *(short8*)(&Bs[n * 64 + p * 8]);
      }
    }
    asm volatile("s_waitcnt lgkmcnt(0)" ::: "memory");  // frags in regs
    __builtin_amdgcn_sched_barrier(0);
    __builtin_amdgcn_s_barrier();   // all waves done READING buf[cur]
    __builtin_amdgcn_sched_barrier(0);

    if (t + 2 < NIT) stage(t + 2, cur);  // overwrite cur slot; overlaps MFMA

#pragma unroll
    for (int s2 = 0; s2 < 2; s2++)
#pragma unroll
      for (int mi = 0; mi < 4; mi++)
#pragma unroll
        for (int ni = 0; ni < 2; ni++)
          acc[mi][ni] = __builtin_amdgcn_mfma_f32_16x16x32_bf16(
              afr[s2][mi], bfr[s2][ni], acc[mi][ni], 0, 0, 0);
  }
  __syncthreads();

  // epilogue: bias(+swish) -> LDS transpose -> coalesced stores
#pragma unroll
  for (int ni = 0; ni < 2; ni++) {
    int colL = wc * 32 + ni * 16 + lrow;
    float bv = bias[(size_t)e * NH + n0 + colL];
#pragma unroll
    for (int mi = 0; mi < 4; mi++) {
#pragma unroll
      for (int r = 0; r < 4; r++) {
        int row = wr * 64 + mi * 16 + kq * 4 + r;
        float v = acc[mi][ni][r] + bv;
        if (SWISH) v = v / (1.0f + __expf(-v));
        if (OUT_BF16)
          ((unsigned short*)smem)[row * 80 + colL] = f2bf(v);
        else
          ((float*)smem)[row * 68 + colL] = v;
      }
    }
  }
  __syncthreads();
  if (OUT_BF16) {
    unsigned short* Y = (unsigned short*)Yv;
#pragma unroll
    for (int i = 0; i < 4; i++) {
      int u = i * 256 + tid;
      int row = u >> 3, c = u & 7;
      if (row >= 64 && s1 < 0) continue;
      int s = (row < 64) ? s0 : s1;
      uint4 v = *(uint4*)(&((unsigned short*)smem)[row * 80 + c * 8]);
      *(uint4*)(Y + ((size_t)(s * NT + (row & 63))) * NH + n0 + c * 8) = v;
    }
  } else {
    float* Y = (float*)Yv;
#pragma unroll
    for (int i = 0; i < 8; i++) {
      int u = i * 256 + tid;
      int row = u >> 4, c = u & 15;
      if (row >= 64 && s1 < 0) continue;
      int s = (row < 64) ? s0 : s1;
      uint4 v = *(uint4*)(&((float*)smem)[row * 68 + c * 4]);
      *(uint4*)(Y + ((size_t)(s * NT + (row & 63))) * NH + n0 + c * 4) = v;
    }
  }
}

// ---------------------------------------------------------------------------
extern "C" void kernel_launch(void* const* d_in, const int* in_sizes, int n_in,
                              void* d_out, int out_size, void* d_ws, size_t ws_size,
                              hipStream_t stream) {
  const float* actions   = (const float*)d_in[0];
  const int*   timesteps = (const int*)d_in[1];
  const int*   cat_ids   = (const int*)d_in[2];
  const float* W1 = (const float*)d_in[3];
  const float* b1 = (const float*)d_in[4];
  const float* W2 = (const float*)d_in[5];
  const float* b2 = (const float*)d_in[6];
  const float* W3 = (const float*)d_in[7];
  const float* b3 = (const float*)d_in[8];

  // ws: Hb 16MB | Wt3 16MB | Wt12 1MB | tvec 512KB | bias2 64KB | tiles
  unsigned short* Hb   = (unsigned short*)d_ws;
  unsigned short* Wt3  = (unsigned short*)((char*)d_ws + (size_t)16777216);
  unsigned short* Wt12 = (unsigned short*)((char*)d_ws + (size_t)33554432);
  float* tvec  = (float*)((char*)d_ws + (size_t)34603008);
  float* bias2 = (float*)((char*)d_ws + (size_t)35127296);
  int* tiles   = (int*)((char*)d_ws + (size_t)35192832);
  int* ntiles  = tiles + 3 * MAXTILES;

  wp_kernel<<<2561, 256, 0, stream>>>(W1, b1, W2, b2, W3, timesteps, cat_ids,
                                      Wt12, bias2, tvec, Wt3, tiles, ntiles);
  gemmh_kernel<<<dim3(2, NB), 256, 0, stream>>>(actions, Wt12, tvec, bias2,
                                                cat_ids, Hb);
  gemm2_kernel<512, false, false, false><<<dim3(8, MAXTILES), 256, 0, stream>>>(
      Hb, nullptr, Wt3, b3, d_out, tiles, ntiles);
}

// Round 5
// 193.483 us; speedup vs baseline: 1.8485x; 1.0101x over previous
//
#include <hip/hip_runtime.h>
#include <hip/hip_bf16.h>

// Problem: B=256, T=64, A=32, H=512, E=32
#define NB 256
#define NT 64
#define NA 32
#define NH 512
#define NE 32
#define MAXTILES 144   // max sum_e ceil(count_e/2) = 128 + 16

typedef short short8 __attribute__((ext_vector_type(8)));
typedef unsigned short ushort8v __attribute__((ext_vector_type(8)));
typedef float f32x4 __attribute__((ext_vector_type(4)));

__device__ __forceinline__ unsigned short f2bf(float f) {
  unsigned int u = __float_as_uint(f);
  u += 0x7FFFu + ((u >> 16) & 1u);   // round-to-nearest-even
  return (unsigned short)(u >> 16);
}

// async global->LDS, 16B per lane; lds dest = wave-uniform base + lane*16
__device__ __forceinline__ void gl2lds16(const void* g, void* l) {
  __builtin_amdgcn_global_load_lds(
      (const __attribute__((address_space(1))) unsigned int*)g,
      (__attribute__((address_space(3))) unsigned int*)l, 16, 0, 0);
}

__device__ __forceinline__ ushort8v cvt8(float4 a, float4 b) {
  ushort8v t;
  t[0] = f2bf(a.x); t[1] = f2bf(a.y); t[2] = f2bf(a.z); t[3] = f2bf(a.w);
  t[4] = f2bf(b.x); t[5] = f2bf(b.y); t[6] = f2bf(b.z); t[7] = f2bf(b.w);
  return t;
}

// prefetch one [16k x 256n] fp32 chunk: per wave-instr = 1KB contiguous half-row
__device__ __forceinline__ void pfld(float2 (&pf)[8], const float* __restrict__ base,
                                     int c, int tid) {
#pragma unroll
  for (int j = 0; j < 8; j++) {
    int u = j * 256 + tid;
    int kk = u >> 7, cc = u & 127;
    pf[j] = *(const float2*)(base + (size_t)(c * 16 + kk) * NH + cc * 2);
  }
}

// ---------------------------------------------------------------------------
// stream_block: K=512 in 32 chunks of [16k x 256n], prefetch DISTANCE 2,
// padded-LDS transpose->bf16, MFMA every 2 chunks. M=32 (As), N=256 (4 waves).
// ---------------------------------------------------------------------------
template <bool BIASDOT>
__device__ __forceinline__ void stream_block(
    const float* __restrict__ Wbase, float* S, unsigned short* Bs,
    const unsigned short* As, const float* b1S, int tid, int w, int lrow,
    int kq, f32x4 (&acc)[2][4], float& bacc) {
  float2 pf[2][8];
  pfld(pf[0], Wbase, 0, tid);
  pfld(pf[1], Wbase, 1, tid);
#pragma unroll 2
  for (int c = 0; c < 32; c++) {
    const int cur = c & 1;
    __syncthreads();  // S free (prev transpose done), Bs[cur] free
#pragma unroll
    for (int j = 0; j < 8; j++) {
      int u = j * 256 + tid;
      int kk = u >> 7, cc = u & 127;
      *(float2*)(&S[kk * 260 + cc * 2]) = pf[cur][j];
    }
    if (c + 2 < 32) pfld(pf[cur], Wbase, c + 2, tid);  // distance-2 refill
    __syncthreads();  // S ready
    {  // transpose-convert column n=tid -> Bs[n][cur*16..], fp32 bias dot
      int n = tid;
      ushort8v pk0, pk1;
#pragma unroll
      for (int kk = 0; kk < 8; kk++) {
        float sv = S[kk * 260 + n];
        pk0[kk] = f2bf(sv);
        if (BIASDOT) bacc += sv * b1S[c * 16 + kk];
      }
#pragma unroll
      for (int kk = 8; kk < 16; kk++) {
        float sv = S[kk * 260 + n];
        pk1[kk - 8] = f2bf(sv);
        if (BIASDOT) bacc += sv * b1S[c * 16 + kk];
      }
      *(ushort8v*)(&Bs[n * 40 + cur * 16]) = pk0;
      *(ushort8v*)(&Bs[n * 40 + cur * 16 + 8]) = pk1;
    }
    if (cur) {
      __syncthreads();  // Bs window complete
      int w2i = c >> 1;
      short8 bf[4], af[2];
#pragma unroll
      for (int ni = 0; ni < 4; ni++)
        bf[ni] = *(short8*)(&Bs[(w * 64 + ni * 16 + lrow) * 40 + kq * 8]);
#pragma unroll
      for (int mi = 0; mi < 2; mi++) {
        int a = mi * 16 + lrow;
        int ck = w2i * 4 + kq;
        af[mi] = *(short8*)(&As[a * 512 + ((ck ^ (a & 7)) << 3)]);
      }
#pragma unroll
      for (int mi = 0; mi < 2; mi++)
#pragma unroll
        for (int ni = 0; ni < 4; ni++)
          acc[mi][ni] = __builtin_amdgcn_mfma_f32_16x16x32_bf16(
              af[mi], bf[ni], acc[mi][ni], 0, 0, 0);
    }
  }
}

// ---------------------------------------------------------------------------
// wp2: all prep work, one launch, four roles:
//   [0,64):    W12  — W12[e] = W1@W2a (bf16 [e][n][a]) + bias2 = b1@W2a + b2
//   [64,128):  tvec — tvec[b] = tau_b@W2b (fp32, raw)
//   [128,640): prep — W3 -> Wt3 bf16 k-blocked [e][kb][n][64] (32KB contig writes)
//   640:       groupk — tiles for the grouped GEMM
// ---------------------------------------------------------------------------
__global__ __launch_bounds__(256) void wp2_kernel(
    const float* __restrict__ W1, const float* __restrict__ b1,
    const float* __restrict__ W2, const float* __restrict__ b2,
    const float* __restrict__ W3, const int* __restrict__ timesteps,
    const int* __restrict__ cat, unsigned short* __restrict__ Wt12,
    float* __restrict__ bias2G, float* __restrict__ tvec,
    unsigned short* __restrict__ Wt3, int* __restrict__ tiles,
    int* __restrict__ ntiles_out) {
  __shared__ __align__(16) unsigned char smem[71936];
  int tid = threadIdx.x;
  int bx = blockIdx.x;

  if (bx >= 128 && bx < 640) {
    // ---------------- prep role: W3 -> Wt3[e][kb][n][64] ----------------
    float* S2 = (float*)smem;                          // [32][260] = 33280
    unsigned short* Bt = (unsigned short*)(smem + 33280);  // [256][72] = 36864
    int id = bx - 128;
    int e = id >> 4, kb = (id >> 1) & 7, nh = id & 1;
    int kt = kb * 64, nt = nh * 256;
#pragma unroll
    for (int h = 0; h < 2; h++) {
      if (h) __syncthreads();
#pragma unroll
      for (int j = 0; j < 16; j++) {  // 32 rows x 1KB half-rows
        int u = j * 256 + tid;
        int kk = u >> 7, cc = u & 127;
        float2 v = *(const float2*)(W3 + ((size_t)e * 512 + kt + h * 32 + kk) * NH +
                                    nt + cc * 2);
        *(float2*)(&S2[kk * 260 + cc * 2]) = v;
      }
      __syncthreads();
      {  // column n=tid -> Bt[n][h*32 + 0..31]
        int n = tid;
#pragma unroll
        for (int q = 0; q < 4; q++) {
          ushort8v pk;
#pragma unroll
          for (int jj = 0; jj < 8; jj++)
            pk[jj] = f2bf(S2[(q * 8 + jj) * 260 + n]);
          *(ushort8v*)(&Bt[n * 72 + h * 32 + q * 8]) = pk;
        }
      }
    }
    __syncthreads();
    {  // write out: 128B per thread, 32KB contiguous per block
      int n = tid;
      unsigned short* dst = Wt3 + (((size_t)e * 8 + kb) * 512 + nt + n) * 64;
#pragma unroll
      for (int q = 0; q < 8; q++)
        *(ushort8v*)(dst + q * 8) = *(ushort8v*)(&Bt[n * 72 + q * 8]);
    }
    return;
  }

  if (bx == 640) {
    // ---------------- groupk role ----------------
    int* cnt = (int*)smem;
    int* off = cnt + 32;
    int* cur = off + 32;
    int* order = cur + 32;
    if (tid < NE) cnt[tid] = 0;
    __syncthreads();
    int e = cat[tid];
    atomicAdd(&cnt[e], 1);
    __syncthreads();
    if (tid == 0) {
      int s = 0;
      for (int i = 0; i < NE; i++) { off[i] = s; cur[i] = s; s += cnt[i]; }
    }
    __syncthreads();
    int p = atomicAdd(&cur[e], 1);
    order[p] = tid;
    __syncthreads();
    if (tid == 0) {
      int nt = 0;
      for (int i = 0; i < NE; i++) {
        for (int j = 0; j < cnt[i]; j += 2) {
          tiles[3 * nt + 0] = i;
          tiles[3 * nt + 1] = order[off[i] + j];
          tiles[3 * nt + 2] = (j + 1 < cnt[i]) ? order[off[i] + j + 1] : -1;
          nt++;
        }
      }
      *ntiles_out = nt;
    }
    return;
  }

  // ---------------- long roles ----------------
  float* S           = (float*)smem;                        // [16][260] 16640
  unsigned short* Bs = (unsigned short*)(smem + 16640);     // [256][40] 20480
  unsigned short* As = (unsigned short*)(smem + 37120);     // [32][512] 32768
  float* b1S         = (float*)(smem + 69888);              // 2048 (W12)
  int* list          = (int*)(smem + 69888);                // 1024 (tvec)
  int* pcnt          = (int*)(smem + 70912);

  int w = tid >> 6, l = tid & 63;
  int lrow = l & 15, kq = l >> 4;

  if (bx < 64) {
    // ---- W12 role ----
    int e = bx >> 1, nh = bx & 1;
    const float* Wbase = W2 + ((size_t)e << 19) + nh * 256;  // W2a half
    const float* W1e = W1 + ((size_t)e << 14);
    {
      float2 v = *(const float2*)(b1 + (size_t)e * NH + tid * 2);
      *(float2*)(&b1S[tid * 2]) = v;
    }
    {  // As <- W1 bf16, XOR-chunked
      int a = tid >> 3, seg = tid & 7;
#pragma unroll
      for (int p = 0; p < 8; p++) {
        const float* src = W1e + (size_t)a * NH + p * 64 + seg * 8;
        float4 v0 = *(const float4*)src;
        float4 v1 = *(const float4*)(src + 4);
        int ch = p * 8 + seg;
        *(ushort8v*)(&As[a * 512 + ((ch ^ (a & 7)) << 3)]) = cvt8(v0, v1);
      }
    }
    f32x4 acc[2][4];
#pragma unroll
    for (int mi = 0; mi < 2; mi++)
#pragma unroll
      for (int ni = 0; ni < 4; ni++) acc[mi][ni] = (f32x4){0.f, 0.f, 0.f, 0.f};
    float bacc = 0.f;
    stream_block<true>(Wbase, S, Bs, As, b1S, tid, w, lrow, kq, acc, bacc);

    __syncthreads();
    unsigned short* Sb = Bs;  // reuse as [256 n][40 a]
#pragma unroll
    for (int mi = 0; mi < 2; mi++)
#pragma unroll
      for (int ni = 0; ni < 4; ni++)
#pragma unroll
        for (int r = 0; r < 4; r++)
          Sb[(w * 64 + ni * 16 + lrow) * 40 + mi * 16 + kq * 4 + r] =
              f2bf(acc[mi][ni][r]);
    bias2G[(size_t)e * NH + nh * 256 + tid] =
        bacc + b2[(size_t)e * NH + nh * 256 + tid];
    __syncthreads();
    {
      int n = tid;
      unsigned short* dst = Wt12 + ((size_t)e * NH + nh * 256 + n) * NA;
#pragma unroll
      for (int q = 0; q < 4; q++)
        *(ushort8v*)(dst + q * 8) = *(ushort8v*)(&Sb[n * 40 + q * 8]);
    }
    return;
  }

  // ---- tvec role ----
  {
    int id = bx - 64;
    int e = id >> 1, nh = id & 1;
    const float* Wbase = W2 + ((size_t)e << 19) + ((size_t)512 * NH) + nh * 256;
    if (tid == 0) *pcnt = 0;
    __syncthreads();
    if (cat[tid] == e) { int p = atomicAdd(pcnt, 1); list[p] = tid; }
    __syncthreads();
    int c = *pcnt;
    if (c == 0) return;
    const float kLog = 0.035977893400931146f;  // ln(10000)/256

    for (int sg = 0; sg * 32 < c; sg++) {
      if (sg) __syncthreads();
      {  // As <- tau rows (32 samples), XOR-chunked
        int a = tid >> 3, seg = tid & 7;
        int si = sg * 32 + a;
        float tv = (si < c) ? (float)timesteps[list[si]] : 0.f;
#pragma unroll
        for (int p = 0; p < 8; p++) {
          ushort8v pk;
#pragma unroll
          for (int q = 0; q < 8; q++) {
            int k = p * 64 + seg * 8 + q;
            float f = expf(-(float)(k & 255) * kLog);
            float ang = tv * f;
            pk[q] = f2bf((k < 256) ? sinf(ang) : cosf(ang));
          }
          int ch = p * 8 + seg;
          *(ushort8v*)(&As[a * 512 + ((ch ^ (a & 7)) << 3)]) = pk;
        }
      }
      f32x4 acc[2][4];
#pragma unroll
      for (int mi = 0; mi < 2; mi++)
#pragma unroll
        for (int ni = 0; ni < 4; ni++) acc[mi][ni] = (f32x4){0.f, 0.f, 0.f, 0.f};
      float dummy = 0.f;
      stream_block<false>(Wbase, S, Bs, As, nullptr, tid, w, lrow, kq, acc, dummy);
#pragma unroll
      for (int mi = 0; mi < 2; mi++)
#pragma unroll
        for (int ni = 0; ni < 4; ni++)
#pragma unroll
          for (int r = 0; r < 4; r++) {
            int a = mi * 16 + kq * 4 + r;
            int si = sg * 32 + a;
            if (si < c)
              tvec[(size_t)list[si] * NH + nh * 256 + w * 64 + ni * 16 + lrow] =
                  acc[mi][ni][r];
          }
    }
  }
}

// ---------------------------------------------------------------------------
// gemmh: hidden layer via FUSED weights. K=32 (one MFMA per fragment):
//   Hb[b*64+t][n] = swish( actions[b][t] @ Wt12[e] + tvec[b][n] + bias2[e][n] )
// ---------------------------------------------------------------------------
__global__ __launch_bounds__(256) void gemmh_kernel(
    const float* __restrict__ actions, const unsigned short* __restrict__ Wt12,
    const float* __restrict__ tvec, const float* __restrict__ bias2,
    const int* __restrict__ cat_ids, unsigned short* __restrict__ Hb) {
  __shared__ __align__(16) unsigned char smem[16384 + 5120 + 33792];
  unsigned short* Ws = (unsigned short*)smem;                   // [256][32] swizzled
  unsigned short* As = (unsigned short*)(smem + 16384);         // [64][40]
  unsigned short* Ts = (unsigned short*)(smem + 16384 + 5120);  // [64][264]

  int b = blockIdx.y, h = blockIdx.x;
  int tid = threadIdx.x;
  int e = cat_ids[b];

  {  // async stage Wt12[e][h*256 .. +256][0..32] -> Ws (chunk swizzle)
    const unsigned short* wsrc = Wt12 + ((size_t)e * NH + h * 256) * NA;
#pragma unroll
    for (int j = 0; j < 4; j++) {
      int u = j * 256 + tid;
      int n = u >> 2, p = u & 3;
      int ch = p ^ ((n >> 1) & 3);
      gl2lds16(wsrc + (size_t)n * NA + ch * 8,
               Ws + (size_t)(j * 256 + (tid & 448)) * 8);
    }
  }
  {  // stage actions (64x32 f32 -> bf16), padded stride 40
    int row = tid >> 2, seg = tid & 3;
    const float* src = actions + (size_t)(b * NT + row) * NA + seg * 8;
    float4 v0 = *(const float4*)(src);
    float4 v1 = *(const float4*)(src + 4);
    *(ushort8v*)(&As[row * 40 + seg * 8]) = cvt8(v0, v1);
  }
  __syncthreads();

  int w = tid >> 6, l = tid & 63;
  int lrow = l & 15, kq = l >> 4;
  short8 af = *(short8*)(&As[(w * 16 + lrow) * 40 + kq * 8]);
  f32x4 zero = {0.f, 0.f, 0.f, 0.f};
  f32x4 acc[16];
#pragma unroll
  for (int ni = 0; ni < 16; ni++) {
    int nn = ni * 16 + lrow;
    int p = kq ^ ((nn >> 1) & 3);
    short8 bfv = *(short8*)(&Ws[nn * 32 + p * 8]);
    acc[ni] = __builtin_amdgcn_mfma_f32_16x16x32_bf16(af, bfv, zero, 0, 0, 0);
  }
#pragma unroll
  for (int ni = 0; ni < 16; ni++) {
    int colL = ni * 16 + lrow;
    float bv = tvec[(size_t)b * NH + h * 256 + colL] +
               bias2[(size_t)e * NH + h * 256 + colL];
#pragma unroll
    for (int r = 0; r < 4; r++) {
      int row = w * 16 + kq * 4 + r;
      float v = acc[ni][r] + bv;
      v = v / (1.0f + __expf(-v));  // swish
      Ts[row * 264 + colL] = f2bf(v);
    }
  }
  __syncthreads();
#pragma unroll
  for (int i = 0; i < 8; i++) {  // coalesced Hb rows
    int u = i * 256 + tid;
    int t = u >> 5, c4 = u & 31;
    uint4 v = *(uint4*)(&Ts[t * 264 + c4 * 8]);
    *(uint4*)(Hb + ((size_t)(b * NT + t)) * NH + h * 256 + c4 * 8) = v;
  }
}

// ---------------------------------------------------------------------------
// Grouped GEMM, 2-phase double-buffered pipeline, counted vmcnt(6).
// B-side reads the k-blocked Wt3 layout [e][kb][n][64]: 8KB contiguous per tile.
// ---------------------------------------------------------------------------
template <int KTOT, bool HASTAU, bool SWISH, bool OUT_BF16>
__global__ __launch_bounds__(256) void gemm2_kernel(
    const unsigned short* __restrict__ Xa, const unsigned short* __restrict__ Xt,
    const unsigned short* __restrict__ Wt, const float* __restrict__ bias,
    void* __restrict__ Yv, const int* __restrict__ tiles,
    const int* __restrict__ pntiles) {
  __shared__ __align__(16) unsigned char smem[49152];  // 2 x (As 16K + Bs 8K)

  int ti = blockIdx.y;
  if (ti >= *pntiles) return;
  int n0 = blockIdx.x * 64;
  int e = tiles[3 * ti], s0 = tiles[3 * ti + 1], s1 = tiles[3 * ti + 2];
  int s1v = (s1 < 0) ? s0 : s1;

  int tid = threadIdx.x;
  int l = tid & 63;
  int wr = (tid >> 7), wc = (tid >> 6) & 1;
  int lrow = l & 15, kq = l >> 4;

  constexpr int NIT = KTOT / 64;

  auto stage = [&](int it, int buf) {
    unsigned short* As = (unsigned short*)(smem + buf * 24576);
    unsigned short* Bs = (unsigned short*)(smem + buf * 24576 + 16384);
    int k0 = it * 64;
#pragma unroll
    for (int j = 0; j < 4; j++) {
      int u = j * 256 + tid;
      int row = u >> 3, p = u & 7;
      int ch = p ^ (row & 7);
      int kk = k0 + ch * 8;
      int s = (row < 64) ? s0 : s1v;
      const unsigned short* src;
      if (HASTAU && kk >= 512)
        src = Xt + (size_t)s * NH + (kk - 512);
      else
        src = Xa + ((size_t)(s * NT + (row & 63))) * NH + kk;
      gl2lds16(src, As + (size_t)(j * 256 + (tid & 448)) * 8);
    }
#pragma unroll
    for (int j = 0; j < 2; j++) {
      int u = j * 256 + tid;
      int n = u >> 3, p = u & 7;
      int ch = p ^ (n & 7);
      gl2lds16(Wt + (((size_t)e * 8 + it) * 512 + n0 + n) * 64 + ch * 8,
               Bs + (size_t)(j * 256 + (tid & 448)) * 8);
    }
  };

  f32x4 acc[4][2];
#pragma unroll
  for (int mi = 0; mi < 4; mi++)
#pragma unroll
    for (int ni = 0; ni < 2; ni++) acc[mi][ni] = (f32x4){0.f, 0.f, 0.f, 0.f};

  stage(0, 0);
  stage(1, 1);

  for (int t = 0; t < NIT; t++) {
    int cur = t & 1;
    unsigned short* As = (unsigned short*)(smem + cur * 24576);
    unsigned short* Bs = (unsigned short*)(smem + cur * 24576 + 16384);

    if (t + 1 < NIT) {
      asm volatile("s_waitcnt vmcnt(6)" ::: "memory");
    } else {
      asm volatile("s_waitcnt vmcnt(0)" ::: "memory");
    }
    __builtin_amdgcn_sched_barrier(0);
    __builtin_amdgcn_s_barrier();
    __builtin_amdgcn_sched_barrier(0);

    short8 afr[2][4], bfr[2][2];
#pragma unroll
    for (int s2 = 0; s2 < 2; s2++) {
#pragma unroll
      for (int mi = 0; mi < 4; mi++) {
        int row = wr * 64 + mi * 16 + lrow;
        int p = (s2 * 4 + kq) ^ (row & 7);
        afr[s2][mi] = *(short8*)(&As[row * 64 + p * 8]);
      }
#pragma unroll
      for (int ni = 0; ni < 2; ni++) {
        int n = wc * 32 + ni * 16 + lrow;
        int p = (s2 * 4 + kq) ^ (n & 7);
        bfr[s2][ni] = *(short8*)(&Bs[n * 64 + p * 8]);
      }
    }
    asm volatile("s_waitcnt lgkmcnt(0)" ::: "memory");
    __builtin_amdgcn_sched_barrier(0);
    __builtin_amdgcn_s_barrier();
    __builtin_amdgcn_sched_barrier(0);

    if (t + 2 < NIT) stage(t + 2, cur);

#pragma unroll
    for (int s2 = 0; s2 < 2; s2++)
#pragma unroll
      for (int mi = 0; mi < 4; mi++)
#pragma unroll
        for (int ni = 0; ni < 2; ni++)
          acc[mi][ni] = __builtin_amdgcn_mfma_f32_16x16x32_bf16(
              afr[s2][mi], bfr[s2][ni], acc[mi][ni], 0, 0, 0);
  }
  __syncthreads();

#pragma unroll
  for (int ni = 0; ni < 2; ni++) {
    int colL = wc * 32 + ni * 16 + lrow;
    float bv = bias[(size_t)e * NH + n0 + colL];
#pragma unroll
    for (int mi = 0; mi < 4; mi++) {
#pragma unroll
      for (int r = 0; r < 4; r++) {
        int row = wr * 64 + mi * 16 + kq * 4 + r;
        float v = acc[mi][ni][r] + bv;
        if (SWISH) v = v / (1.0f + __expf(-v));
        if (OUT_BF16)
          ((unsigned short*)smem)[row * 80 + colL] = f2bf(v);
        else
          ((float*)smem)[row * 68 + colL] = v;
      }
    }
  }
  __syncthreads();
  if (OUT_BF16) {
    unsigned short* Y = (unsigned short*)Yv;
#pragma unroll
    for (int i = 0; i < 4; i++) {
      int u = i * 256 + tid;
      int row = u >> 3, c = u & 7;
      if (row >= 64 && s1 < 0) continue;
      int s = (row < 64) ? s0 : s1;
      uint4 v = *(uint4*)(&((unsigned short*)smem)[row * 80 + c * 8]);
      *(uint4*)(Y + ((size_t)(s * NT + (row & 63))) * NH + n0 + c * 8) = v;
    }
  } else {
    float* Y = (float*)Yv;
#pragma unroll
    for (int i = 0; i < 8; i++) {
      int u = i * 256 + tid;
      int row = u >> 4, c = u & 15;
      if (row >= 64 && s1 < 0) continue;
      int s = (row < 64) ? s0 : s1;
      uint4 v = *(uint4*)(&((float*)smem)[row * 68 + c * 4]);
      *(uint4*)(Y + ((size_t)(s * NT + (row & 63))) * NH + n0 + c * 4) = v;
    }
  }
}

// ---------------------------------------------------------------------------
extern "C" void kernel_launch(void* const* d_in, const int* in_sizes, int n_in,
                              void* d_out, int out_size, void* d_ws, size_t ws_size,
                              hipStream_t stream) {
  const float* actions   = (const float*)d_in[0];
  const int*   timesteps = (const int*)d_in[1];
  const int*   cat_ids   = (const int*)d_in[2];
  const float* W1 = (const float*)d_in[3];
  const float* b1 = (const float*)d_in[4];
  const float* W2 = (const float*)d_in[5];
  const float* b2 = (const float*)d_in[6];
  const float* W3 = (const float*)d_in[7];
  const float* b3 = (const float*)d_in[8];

  // ws: Hb 16MB | Wt3 16MB (k-blocked) | Wt12 1MB | tvec 512KB | bias2 | tiles
  unsigned short* Hb   = (unsigned short*)d_ws;
  unsigned short* Wt3  = (unsigned short*)((char*)d_ws + (size_t)16777216);
  unsigned short* Wt12 = (unsigned short*)((char*)d_ws + (size_t)33554432);
  float* tvec  = (float*)((char*)d_ws + (size_t)34603008);
  float* bias2 = (float*)((char*)d_ws + (size_t)35127296);
  int* tiles   = (int*)((char*)d_ws + (size_t)35192832);
  int* ntiles  = tiles + 3 * MAXTILES;

  wp2_kernel<<<641, 256, 0, stream>>>(W1, b1, W2, b2, W3, timesteps, cat_ids,
                                      Wt12, bias2, tvec, Wt3, tiles, ntiles);
  gemmh_kernel<<<dim3(2, NB), 256, 0, stream>>>(actions, Wt12, tvec, bias2,
                                                cat_ids, Hb);
  gemm2_kernel<512, false, false, false><<<dim3(8, MAXTILES), 256, 0, stream>>>(
      Hb, nullptr, Wt3, b3, d_out, tiles, ntiles);
}

// Round 6
// 188.400 us; speedup vs baseline: 1.8984x; 1.0270x over previous
//
#include <hip/hip_runtime.h>
#include <hip/hip_bf16.h>

// Problem: B=256, T=64, A=32, H=512, E=32
#define NB 256
#define NT 64
#define NA 32
#define NH 512
#define NE 32
#define MAXTILES 144   // max sum_e ceil(count_e/2) = 128 + 16

typedef short short8 __attribute__((ext_vector_type(8)));
typedef unsigned short ushort8v __attribute__((ext_vector_type(8)));
typedef unsigned short ushort4v __attribute__((ext_vector_type(4)));
typedef float f32x4 __attribute__((ext_vector_type(4)));

__device__ __forceinline__ unsigned short f2bf(float f) {
  unsigned int u = __float_as_uint(f);
  u += 0x7FFFu + ((u >> 16) & 1u);   // round-to-nearest-even
  return (unsigned short)(u >> 16);
}

// async global->LDS, 16B per lane; lds dest = wave-uniform base + lane*16
__device__ __forceinline__ void gl2lds16(const void* g, void* l) {
  __builtin_amdgcn_global_load_lds(
      (const __attribute__((address_space(1))) unsigned int*)g,
      (__attribute__((address_space(3))) unsigned int*)l, 16, 0, 0);
}

__device__ __forceinline__ ushort8v cvt8(float4 a, float4 b) {
  ushort8v t;
  t[0] = f2bf(a.x); t[1] = f2bf(a.y); t[2] = f2bf(a.z); t[3] = f2bf(a.w);
  t[4] = f2bf(b.x); t[5] = f2bf(b.y); t[6] = f2bf(b.z); t[7] = f2bf(b.w);
  return t;
}

// prefetch one [32k x 128n] fp32 chunk: per wave-instr = one 512B row segment
__device__ __forceinline__ void pfld2(float2 (&pf)[8], const float* __restrict__ base,
                                      int c, int tid) {
#pragma unroll
  for (int j = 0; j < 8; j++) {
    int u = j * 256 + tid;
    int kk = u >> 6, cc = u & 63;
    pf[j] = *(const float2*)(base + (size_t)(c * 32 + kk) * NH + cc * 2);
  }
}

// ---------------------------------------------------------------------------
// stream2: K=512 in 16 chunks of [32k x 128n], reg prefetch distance 2,
// padded-LDS transpose->bf16, one MFMA k-step per chunk. N=128 (4 waves x 32).
// AStage fills As[32][40] (bf16, rows = A-operand rows) for chunk c.
// ---------------------------------------------------------------------------
template <bool BIASDOT, typename AStage>
__device__ __forceinline__ void stream2(
    const float* __restrict__ Wbase, float* S, unsigned short* Bs,
    unsigned short* As, const float* b1S, int tid, int w, int lrow, int kq,
    f32x4 (&acc)[2][2], float& bacc, AStage&& astage) {
  float2 pf[2][8];
  pfld2(pf[0], Wbase, 0, tid);
  pfld2(pf[1], Wbase, 1, tid);
#pragma unroll 2
  for (int c = 0; c < 16; c++) {
    const int cur = c & 1;
    __syncthreads();  // B1: S/Bs/As free (prev phase-3 reads done)
#pragma unroll
    for (int j = 0; j < 8; j++) {
      int u = j * 256 + tid;
      int kk = u >> 6, cc = u & 63;
      *(float2*)(&S[kk * 132 + cc * 2]) = pf[cur][j];
    }
    astage(c);                                         // As for chunk c
    if (c + 2 < 16) pfld2(pf[cur], Wbase, c + 2, tid); // distance-2 refill
    __syncthreads();  // B2: S/As ready
    {  // transpose-convert: thread owns col n, k-half h2 (+ fp32 bias dot)
      int n = tid >> 1, h2 = tid & 1;
      ushort8v p0, p1;
#pragma unroll
      for (int kk = 0; kk < 8; kk++) {
        float sv = S[(h2 * 16 + kk) * 132 + n];
        p0[kk] = f2bf(sv);
        if (BIASDOT) bacc += sv * b1S[c * 32 + h2 * 16 + kk];
      }
#pragma unroll
      for (int kk = 8; kk < 16; kk++) {
        float sv = S[(h2 * 16 + kk) * 132 + n];
        p1[kk - 8] = f2bf(sv);
        if (BIASDOT) bacc += sv * b1S[c * 32 + h2 * 16 + kk];
      }
      *(ushort8v*)(&Bs[n * 40 + h2 * 16]) = p0;
      *(ushort8v*)(&Bs[n * 40 + h2 * 16 + 8]) = p1;
    }
    __syncthreads();  // B3: Bs ready
    short8 bf[2], af[2];
#pragma unroll
    for (int ni = 0; ni < 2; ni++)
      bf[ni] = *(short8*)(&Bs[(w * 32 + ni * 16 + lrow) * 40 + kq * 8]);
#pragma unroll
    for (int mi = 0; mi < 2; mi++)
      af[mi] = *(short8*)(&As[(mi * 16 + lrow) * 40 + kq * 8]);
#pragma unroll
    for (int mi = 0; mi < 2; mi++)
#pragma unroll
      for (int ni = 0; ni < 2; ni++)
        acc[mi][ni] = __builtin_amdgcn_mfma_f32_16x16x32_bf16(
            af[mi], bf[ni], acc[mi][ni], 0, 0, 0);
  }
}

// ---------------------------------------------------------------------------
// wp3: all prep work, one launch, four roles (long roles dispatched FIRST):
//   [0,128):    W12  — W12[e] = W1@W2a (bf16 [e][n][a]) + bias2 = b1@W2a + b2
//   [128,256):  tvec — tvec[b] = tau_b@W2b (fp32, raw)
//   [256,768):  prep — W3 -> Wt3 bf16 k-blocked [e][kb][n][64]
//   768:        groupk — tiles for the grouped GEMM
// ---------------------------------------------------------------------------
__global__ __launch_bounds__(256) void wp3_kernel(
    const float* __restrict__ W1, const float* __restrict__ b1,
    const float* __restrict__ W2, const float* __restrict__ b2,
    const float* __restrict__ W3, const int* __restrict__ timesteps,
    const int* __restrict__ cat, unsigned short* __restrict__ Wt12,
    float* __restrict__ bias2G, float* __restrict__ tvec,
    unsigned short* __restrict__ Wt3, int* __restrict__ tiles,
    int* __restrict__ ntiles_out) {
  __shared__ __align__(16) unsigned char smem[33280];
  int tid = threadIdx.x;
  int bx = blockIdx.x;

  if (bx >= 256 && bx < 768) {
    // ---------------- prep role: W3 -> Wt3[e][kb][n][64] ----------------
    float* S2 = (float*)smem;  // [32][260] = 33280
    int id = bx - 256;
    int e = id >> 4, kb = (id >> 1) & 7, nh = id & 1;
    int kt = kb * 64, nt = nh * 256;
    ushort8v o[8];
#pragma unroll
    for (int h = 0; h < 2; h++) {
      if (h) __syncthreads();  // S2 free
#pragma unroll
      for (int j = 0; j < 16; j++) {  // 32 rows x 1KB rows
        int u = j * 256 + tid;
        int kk = u >> 7, cc = u & 127;
        float2 v = *(const float2*)(W3 + ((size_t)e * 512 + kt + h * 32 + kk) * NH +
                                    nt + cc * 2);
        *(float2*)(&S2[kk * 260 + cc * 2]) = v;
      }
      __syncthreads();  // S2 ready
      {  // column n=tid -> regs
        int n = tid;
#pragma unroll
        for (int q = 0; q < 4; q++) {
          ushort8v pk;
#pragma unroll
          for (int jj = 0; jj < 8; jj++)
            pk[jj] = f2bf(S2[(q * 8 + jj) * 260 + n]);
          o[h * 4 + q] = pk;
        }
      }
    }
    {  // write out: 128B per thread, 32KB contiguous per block
      int n = tid;
      unsigned short* dst = Wt3 + (((size_t)e * 8 + kb) * 512 + nt + n) * 64;
#pragma unroll
      for (int q = 0; q < 8; q++) *(ushort8v*)(dst + q * 8) = o[q];
    }
    return;
  }

  if (bx == 768) {
    // ---------------- groupk role ----------------
    int* cnt = (int*)smem;
    int* off = cnt + 32;
    int* cur = off + 32;
    int* order = cur + 32;
    if (tid < NE) cnt[tid] = 0;
    __syncthreads();
    int e = cat[tid];
    atomicAdd(&cnt[e], 1);
    __syncthreads();
    if (tid == 0) {
      int s = 0;
      for (int i = 0; i < NE; i++) { off[i] = s; cur[i] = s; s += cnt[i]; }
    }
    __syncthreads();
    int p = atomicAdd(&cur[e], 1);
    order[p] = tid;
    __syncthreads();
    if (tid == 0) {
      int nt = 0;
      for (int i = 0; i < NE; i++) {
        for (int j = 0; j < cnt[i]; j += 2) {
          tiles[3 * nt + 0] = i;
          tiles[3 * nt + 1] = order[off[i] + j];
          tiles[3 * nt + 2] = (j + 1 < cnt[i]) ? order[off[i] + j + 1] : -1;
          nt++;
        }
      }
      *ntiles_out = nt;
    }
    return;
  }

  // ---------------- long roles (N=128 per block) ----------------
  float* S           = (float*)smem;                     // [32][132] 16896
  unsigned short* Bs = (unsigned short*)(smem + 16896);  // [128][40] 10240
  unsigned short* As = (unsigned short*)(smem + 27136);  // [32][40]   2560
  float* b1S         = (float*)(smem + 29696);           // 2048 (W12)
  float* tauT        = (float*)(smem + 31744);           // 128  (tvec)
  int* list          = (int*)(smem + 31872);             // 1024 (tvec)
  int* pcnt          = (int*)(smem + 32896);

  int w = tid >> 6, l = tid & 63;
  int lrow = l & 15, kq = l >> 4;

  if (bx < 128) {
    // ---- W12 role: (e, n-quarter) ----
    int e = bx >> 2, nq = bx & 3;
    const float* Wbase = W2 + ((size_t)e << 19) + nq * 128;  // W2a quarter
    const float* W1e = W1 + ((size_t)e << 14);
    {
      float2 v = *(const float2*)(b1 + (size_t)e * NH + tid * 2);
      *(float2*)(&b1S[tid * 2]) = v;
    }
    int aa = tid >> 3, seg = tid & 7;
    float4 pfW = *(const float4*)(W1e + (size_t)aa * NH + seg * 4);
    f32x4 acc[2][2];
#pragma unroll
    for (int mi = 0; mi < 2; mi++)
#pragma unroll
      for (int ni = 0; ni < 2; ni++) acc[mi][ni] = (f32x4){0.f, 0.f, 0.f, 0.f};
    float bacc = 0.f;

    stream2<true>(Wbase, S, Bs, As, b1S, tid, w, lrow, kq, acc, bacc,
                  [&](int c) {
                    ushort4v pk;
                    pk[0] = f2bf(pfW.x); pk[1] = f2bf(pfW.y);
                    pk[2] = f2bf(pfW.z); pk[3] = f2bf(pfW.w);
                    *(ushort4v*)(&As[aa * 40 + seg * 4]) = pk;
                    if (c + 1 < 16)
                      pfW = *(const float4*)(W1e + (size_t)aa * NH +
                                             (c + 1) * 32 + seg * 4);
                  });

    __syncthreads();  // all MFMA reads done; reuse Bs as repack buffer
    unsigned short* Sb = Bs;  // [128 n][40 a]
#pragma unroll
    for (int mi = 0; mi < 2; mi++)
#pragma unroll
      for (int ni = 0; ni < 2; ni++)
#pragma unroll
        for (int r = 0; r < 4; r++)
          Sb[(w * 32 + ni * 16 + lrow) * 40 + mi * 16 + kq * 4 + r] =
              f2bf(acc[mi][ni][r]);
    {  // bias2: combine k-halves across lane pairs
      float bsum = bacc + __shfl_xor(bacc, 1);
      if ((tid & 1) == 0) {
        int n = tid >> 1;
        bias2G[(size_t)e * NH + nq * 128 + n] =
            bsum + b2[(size_t)e * NH + nq * 128 + n];
      }
    }
    __syncthreads();
    {  // Wt12 out: 32B per thread, coalesced
      int n = tid >> 1, q = tid & 1;
      unsigned short* dst = Wt12 + ((size_t)e * NH + nq * 128 + n) * NA + q * 16;
      *(ushort8v*)(dst) = *(ushort8v*)(&Sb[n * 40 + q * 16]);
      *(ushort8v*)(dst + 8) = *(ushort8v*)(&Sb[n * 40 + q * 16 + 8]);
    }
    return;
  }

  // ---- tvec role: (e, n-quarter) ----
  {
    int id = bx - 128;
    int e = id >> 2, nq = id & 3;
    const float* Wbase = W2 + ((size_t)e << 19) + ((size_t)512 * NH) + nq * 128;
    if (tid == 0) *pcnt = 0;
    __syncthreads();
    if (cat[tid] == e) { int p = atomicAdd(pcnt, 1); list[p] = tid; }
    __syncthreads();
    int c = *pcnt;
    if (c == 0) return;
    const float kLog = 0.035977893400931146f;  // ln(10000)/256
    int ss = tid >> 3, seg = tid & 7;

    for (int sg = 0; sg * 32 < c; sg++) {
      if (tid < 32) {
        int si = sg * 32 + tid;
        tauT[tid] = (si < c) ? (float)timesteps[list[si]] : 0.f;
      }
      // (first B1 barrier inside stream2 publishes tauT)
      f32x4 acc[2][2];
#pragma unroll
      for (int mi = 0; mi < 2; mi++)
#pragma unroll
        for (int ni = 0; ni < 2; ni++) acc[mi][ni] = (f32x4){0.f, 0.f, 0.f, 0.f};
      float dummy = 0.f;

      stream2<false>(Wbase, S, Bs, As, nullptr, tid, w, lrow, kq, acc, dummy,
                     [&](int cch) {
                       float tv = tauT[ss];
                       ushort4v pk;
#pragma unroll
                       for (int q = 0; q < 4; q++) {
                         int kg = cch * 32 + seg * 4 + q;
                         float f = expf(-(float)(kg & 255) * kLog);
                         float ang = tv * f;
                         pk[q] = f2bf((kg < 256) ? sinf(ang) : cosf(ang));
                       }
                       *(ushort4v*)(&As[ss * 40 + seg * 4]) = pk;
                     });
#pragma unroll
      for (int mi = 0; mi < 2; mi++)
#pragma unroll
        for (int ni = 0; ni < 2; ni++)
#pragma unroll
          for (int r = 0; r < 4; r++) {
            int si = sg * 32 + mi * 16 + kq * 4 + r;
            if (si < c)
              tvec[(size_t)list[si] * NH + nq * 128 + w * 32 + ni * 16 + lrow] =
                  acc[mi][ni][r];
          }
      __syncthreads();  // tauT/As free before next group
    }
  }
}

// ---------------------------------------------------------------------------
// gemmh: hidden layer via FUSED weights. K=32 (one MFMA per fragment):
//   Hb[b*64+t][n] = swish( actions[b][t] @ Wt12[e] + tvec[b][n] + bias2[e][n] )
// ---------------------------------------------------------------------------
__global__ __launch_bounds__(256) void gemmh_kernel(
    const float* __restrict__ actions, const unsigned short* __restrict__ Wt12,
    const float* __restrict__ tvec, const float* __restrict__ bias2,
    const int* __restrict__ cat_ids, unsigned short* __restrict__ Hb) {
  __shared__ __align__(16) unsigned char smem[16384 + 5120 + 33792];
  unsigned short* Ws = (unsigned short*)smem;                   // [256][32] swizzled
  unsigned short* As = (unsigned short*)(smem + 16384);         // [64][40]
  unsigned short* Ts = (unsigned short*)(smem + 16384 + 5120);  // [64][264]

  int b = blockIdx.y, h = blockIdx.x;
  int tid = threadIdx.x;
  int e = cat_ids[b];

  {  // async stage Wt12[e][h*256 .. +256][0..32] -> Ws (chunk swizzle)
    const unsigned short* wsrc = Wt12 + ((size_t)e * NH + h * 256) * NA;
#pragma unroll
    for (int j = 0; j < 4; j++) {
      int u = j * 256 + tid;
      int n = u >> 2, p = u & 3;
      int ch = p ^ ((n >> 1) & 3);
      gl2lds16(wsrc + (size_t)n * NA + ch * 8,
               Ws + (size_t)(j * 256 + (tid & 448)) * 8);
    }
  }
  {  // stage actions (64x32 f32 -> bf16), padded stride 40
    int row = tid >> 2, seg = tid & 3;
    const float* src = actions + (size_t)(b * NT + row) * NA + seg * 8;
    float4 v0 = *(const float4*)(src);
    float4 v1 = *(const float4*)(src + 4);
    *(ushort8v*)(&As[row * 40 + seg * 8]) = cvt8(v0, v1);
  }
  __syncthreads();

  int w = tid >> 6, l = tid & 63;
  int lrow = l & 15, kq = l >> 4;
  short8 af = *(short8*)(&As[(w * 16 + lrow) * 40 + kq * 8]);
  f32x4 zero = {0.f, 0.f, 0.f, 0.f};
  f32x4 acc[16];
#pragma unroll
  for (int ni = 0; ni < 16; ni++) {
    int nn = ni * 16 + lrow;
    int p = kq ^ ((nn >> 1) & 3);
    short8 bfv = *(short8*)(&Ws[nn * 32 + p * 8]);
    acc[ni] = __builtin_amdgcn_mfma_f32_16x16x32_bf16(af, bfv, zero, 0, 0, 0);
  }
#pragma unroll
  for (int ni = 0; ni < 16; ni++) {
    int colL = ni * 16 + lrow;
    float bv = tvec[(size_t)b * NH + h * 256 + colL] +
               bias2[(size_t)e * NH + h * 256 + colL];
#pragma unroll
    for (int r = 0; r < 4; r++) {
      int row = w * 16 + kq * 4 + r;
      float v = acc[ni][r] + bv;
      v = v / (1.0f + __expf(-v));  // swish
      Ts[row * 264 + colL] = f2bf(v);
    }
  }
  __syncthreads();
#pragma unroll
  for (int i = 0; i < 8; i++) {  // coalesced Hb rows
    int u = i * 256 + tid;
    int t = u >> 5, c4 = u & 31;
    uint4 v = *(uint4*)(&Ts[t * 264 + c4 * 8]);
    *(uint4*)(Hb + ((size_t)(b * NT + t)) * NH + h * 256 + c4 * 8) = v;
  }
}

// ---------------------------------------------------------------------------
// Grouped GEMM, 2-phase double-buffered pipeline, counted vmcnt(6).
// B-side reads the k-blocked Wt3 layout [e][kb][n][64]: 8KB contiguous per tile.
// ---------------------------------------------------------------------------
template <int KTOT, bool HASTAU, bool SWISH, bool OUT_BF16>
__global__ __launch_bounds__(256) void gemm2_kernel(
    const unsigned short* __restrict__ Xa, const unsigned short* __restrict__ Xt,
    const unsigned short* __restrict__ Wt, const float* __restrict__ bias,
    void* __restrict__ Yv, const int* __restrict__ tiles,
    const int* __restrict__ pntiles) {
  __shared__ __align__(16) unsigned char smem[49152];  // 2 x (As 16K + Bs 8K)

  int ti = blockIdx.y;
  if (ti >= *pntiles) return;
  int n0 = blockIdx.x * 64;
  int e = tiles[3 * ti], s0 = tiles[3 * ti + 1], s1 = tiles[3 * ti + 2];
  int s1v = (s1 < 0) ? s0 : s1;

  int tid = threadIdx.x;
  int l = tid & 63;
  int wr = (tid >> 7), wc = (tid >> 6) & 1;
  int lrow = l & 15, kq = l >> 4;

  constexpr int NIT = KTOT / 64;

  auto stage = [&](int it, int buf) {
    unsigned short* As = (unsigned short*)(smem + buf * 24576);
    unsigned short* Bs = (unsigned short*)(smem + buf * 24576 + 16384);
    int k0 = it * 64;
#pragma unroll
    for (int j = 0; j < 4; j++) {
      int u = j * 256 + tid;
      int row = u >> 3, p = u & 7;
      int ch = p ^ (row & 7);
      int kk = k0 + ch * 8;
      int s = (row < 64) ? s0 : s1v;
      const unsigned short* src;
      if (HASTAU && kk >= 512)
        src = Xt + (size_t)s * NH + (kk - 512);
      else
        src = Xa + ((size_t)(s * NT + (row & 63))) * NH + kk;
      gl2lds16(src, As + (size_t)(j * 256 + (tid & 448)) * 8);
    }
#pragma unroll
    for (int j = 0; j < 2; j++) {
      int u = j * 256 + tid;
      int n = u >> 3, p = u & 7;
      int ch = p ^ (n & 7);
      gl2lds16(Wt + (((size_t)e * 8 + it) * 512 + n0 + n) * 64 + ch * 8,
               Bs + (size_t)(j * 256 + (tid & 448)) * 8);
    }
  };

  f32x4 acc[4][2];
#pragma unroll
  for (int mi = 0; mi < 4; mi++)
#pragma unroll
    for (int ni = 0; ni < 2; ni++) acc[mi][ni] = (f32x4){0.f, 0.f, 0.f, 0.f};

  stage(0, 0);
  stage(1, 1);

  for (int t = 0; t < NIT; t++) {
    int cur = t & 1;
    unsigned short* As = (unsigned short*)(smem + cur * 24576);
    unsigned short* Bs = (unsigned short*)(smem + cur * 24576 + 16384);

    if (t + 1 < NIT) {
      asm volatile("s_waitcnt vmcnt(6)" ::: "memory");
    } else {
      asm volatile("s_waitcnt vmcnt(0)" ::: "memory");
    }
    __builtin_amdgcn_sched_barrier(0);
    __builtin_amdgcn_s_barrier();
    __builtin_amdgcn_sched_barrier(0);

    short8 afr[2][4], bfr[2][2];
#pragma unroll
    for (int s2 = 0; s2 < 2; s2++) {
#pragma unroll
      for (int mi = 0; mi < 4; mi++) {
        int row = wr * 64 + mi * 16 + lrow;
        int p = (s2 * 4 + kq) ^ (row & 7);
        afr[s2][mi] = *(short8*)(&As[row * 64 + p * 8]);
      }
#pragma unroll
      for (int ni = 0; ni < 2; ni++) {
        int n = wc * 32 + ni * 16 + lrow;
        int p = (s2 * 4 + kq) ^ (n & 7);
        bfr[s2][ni] = *(short8*)(&Bs[n * 64 + p * 8]);
      }
    }
    asm volatile("s_waitcnt lgkmcnt(0)" ::: "memory");
    __builtin_amdgcn_sched_barrier(0);
    __builtin_amdgcn_s_barrier();
    __builtin_amdgcn_sched_barrier(0);

    if (t + 2 < NIT) stage(t + 2, cur);

#pragma unroll
    for (int s2 = 0; s2 < 2; s2++)
#pragma unroll
      for (int mi = 0; mi < 4; mi++)
#pragma unroll
        for (int ni = 0; ni < 2; ni++)
          acc[mi][ni] = __builtin_amdgcn_mfma_f32_16x16x32_bf16(
              afr[s2][mi], bfr[s2][ni], acc[mi][ni], 0, 0, 0);
  }
  __syncthreads();

#pragma unroll
  for (int ni = 0; ni < 2; ni++) {
    int colL = wc * 32 + ni * 16 + lrow;
    float bv = bias[(size_t)e * NH + n0 + colL];
#pragma unroll
    for (int mi = 0; mi < 4; mi++) {
#pragma unroll
      for (int r = 0; r < 4; r++) {
        int row = wr * 64 + mi * 16 + kq * 4 + r;
        float v = acc[mi][ni][r] + bv;
        if (SWISH) v = v / (1.0f + __expf(-v));
        if (OUT_BF16)
          ((unsigned short*)smem)[row * 80 + colL] = f2bf(v);
        else
          ((float*)smem)[row * 68 + colL] = v;
      }
    }
  }
  __syncthreads();
  if (OUT_BF16) {
    unsigned short* Y = (unsigned short*)Yv;
#pragma unroll
    for (int i = 0; i < 4; i++) {
      int u = i * 256 + tid;
      int row = u >> 3, c = u & 7;
      if (row >= 64 && s1 < 0) continue;
      int s = (row < 64) ? s0 : s1;
      uint4 v = *(uint4*)(&((unsigned short*)smem)[row * 80 + c * 8]);
      *(uint4*)(Y + ((size_t)(s * NT + (row & 63))) * NH + n0 + c * 8) = v;
    }
  } else {
    float* Y = (float*)Yv;
#pragma unroll
    for (int i = 0; i < 8; i++) {
      int u = i * 256 + tid;
      int row = u >> 4, c = u & 15;
      if (row >= 64 && s1 < 0) continue;
      int s = (row < 64) ? s0 : s1;
      uint4 v = *(uint4*)(&((float*)smem)[row * 68 + c * 4]);
      *(uint4*)(Y + ((size_t)(s * NT + (row & 63))) * NH + n0 + c * 4) = v;
    }
  }
}

// ---------------------------------------------------------------------------
extern "C" void kernel_launch(void* const* d_in, const int* in_sizes, int n_in,
                              void* d_out, int out_size, void* d_ws, size_t ws_size,
                              hipStream_t stream) {
  const float* actions   = (const float*)d_in[0];
  const int*   timesteps = (const int*)d_in[1];
  const int*   cat_ids   = (const int*)d_in[2];
  const float* W1 = (const float*)d_in[3];
  const float* b1 = (const float*)d_in[4];
  const float* W2 = (const float*)d_in[5];
  const float* b2 = (const float*)d_in[6];
  const float* W3 = (const float*)d_in[7];
  const float* b3 = (const float*)d_in[8];

  // ws: Hb 16MB | Wt3 16MB (k-blocked) | Wt12 1MB | tvec 512KB | bias2 | tiles
  unsigned short* Hb   = (unsigned short*)d_ws;
  unsigned short* Wt3  = (unsigned short*)((char*)d_ws + (size_t)16777216);
  unsigned short* Wt12 = (unsigned short*)((char*)d_ws + (size_t)33554432);
  float* tvec  = (float*)((char*)d_ws + (size_t)34603008);
  float* bias2 = (float*)((char*)d_ws + (size_t)35127296);
  int* tiles   = (int*)((char*)d_ws + (size_t)35192832);
  int* ntiles  = tiles + 3 * MAXTILES;

  wp3_kernel<<<769, 256, 0, stream>>>(W1, b1, W2, b2, W3, timesteps, cat_ids,
                                      Wt12, bias2, tvec, Wt3, tiles, ntiles);
  gemmh_kernel<<<dim3(2, NB), 256, 0, stream>>>(actions, Wt12, tvec, bias2,
                                                cat_ids, Hb);
  gemm2_kernel<512, false, false, false><<<dim3(8, MAXTILES), 256, 0, stream>>>(
      Hb, nullptr, Wt3, b3, d_out, tiles, ntiles);
}

// Round 7
// 187.357 us; speedup vs baseline: 1.9090x; 1.0056x over previous
//
#include <hip/hip_runtime.h>
#include <hip/hip_bf16.h>

// Problem: B=256, T=64, A=32, H=512, E=32
#define NB 256
#define NT 64
#define NA 32
#define NH 512
#define NE 32
#define MAXTILES 144   // max sum_e ceil(count_e/2) = 128 + 16

typedef short short8 __attribute__((ext_vector_type(8)));
typedef unsigned short ushort8v __attribute__((ext_vector_type(8)));
typedef unsigned short ushort4v __attribute__((ext_vector_type(4)));
typedef float f32x4 __attribute__((ext_vector_type(4)));

__device__ __forceinline__ unsigned short f2bf(float f) {
  unsigned int u = __float_as_uint(f);
  u += 0x7FFFu + ((u >> 16) & 1u);   // round-to-nearest-even
  return (unsigned short)(u >> 16);
}

// async global->LDS, 16B per lane; lds dest = wave-uniform base + lane*16
__device__ __forceinline__ void gl2lds16(const void* g, void* l) {
  __builtin_amdgcn_global_load_lds(
      (const __attribute__((address_space(1))) unsigned int*)g,
      (__attribute__((address_space(3))) unsigned int*)l, 16, 0, 0);
}

__device__ __forceinline__ ushort8v cvt8(float4 a, float4 b) {
  ushort8v t;
  t[0] = f2bf(a.x); t[1] = f2bf(a.y); t[2] = f2bf(a.z); t[3] = f2bf(a.w);
  t[4] = f2bf(b.x); t[5] = f2bf(b.y); t[6] = f2bf(b.z); t[7] = f2bf(b.w);
  return t;
}

// LDS-only barrier: lgkmcnt(0) + s_barrier, NO vmcnt drain (the __syncthreads
// vmcnt(0) drain was killing the register prefetch pipeline — r6 post-mortem).
__device__ __forceinline__ void bar_lgkm() {
  asm volatile("s_waitcnt lgkmcnt(0)" ::: "memory");
  __builtin_amdgcn_sched_barrier(0);
  __builtin_amdgcn_s_barrier();
  __builtin_amdgcn_sched_barrier(0);
}

// prefetch one [32k x 128n] fp32 chunk: per wave-instr = one 512B row segment
__device__ __forceinline__ void pfld2(float2 (&pf)[8], const float* __restrict__ base,
                                      int c, int tid) {
#pragma unroll
  for (int j = 0; j < 8; j++) {
    int u = j * 256 + tid;
    int kk = u >> 6, cc = u & 63;
    pf[j] = *(const float2*)(base + (size_t)(c * 32 + kk) * NH + cc * 2);
  }
}

// ---------------------------------------------------------------------------
// stream2: K=512 in 16 chunks of [32k x 128n], reg prefetch distance 2 that
// STAYS IN FLIGHT across barriers (raw s_barrier + lgkm-only waits; compiler
// inserts counted vmcnt before pf use). One MFMA k-step per chunk.
// issueA(c,slot): issue global loads for A-operand chunk c into reg slot.
// storeA(c,slot): convert/compute and write As[32][40] for chunk c.
// ---------------------------------------------------------------------------
template <bool BIASDOT, typename IssueA, typename StoreA>
__device__ __forceinline__ void stream2(
    const float* __restrict__ Wbase, float* S, unsigned short* Bs,
    unsigned short* As, const float* b1S, int tid, int w, int lrow, int kq,
    f32x4 (&acc)[2][2], float& bacc, IssueA&& issueA, StoreA&& storeA) {
  float2 pf[2][8];
  pfld2(pf[0], Wbase, 0, tid);
  issueA(0, 0);
  pfld2(pf[1], Wbase, 1, tid);
  issueA(1, 1);
#pragma unroll 2
  for (int c = 0; c < 16; c++) {
    const int cur = c & 1;
    bar_lgkm();  // B1: S/Bs/As free (all waves past prev MFMA reads)
#pragma unroll
    for (int j = 0; j < 8; j++) {
      int u = j * 256 + tid;
      int kk = u >> 6, cc = u & 63;
      *(float2*)(&S[kk * 132 + cc * 2]) = pf[cur][j];
    }
    storeA(c, cur);
    if (c + 2 < 16) {  // distance-2 refill; loads stay in flight across bars
      pfld2(pf[cur], Wbase, c + 2, tid);
      issueA(c + 2, cur);
    }
    bar_lgkm();  // B2: S/As visible
    {  // transpose-convert: thread owns col n, k-half h2 (+ fp32 bias dot)
      int n = tid >> 1, h2 = tid & 1;
      ushort8v p0, p1;
#pragma unroll
      for (int kk = 0; kk < 8; kk++) {
        float sv = S[(h2 * 16 + kk) * 132 + n];
        p0[kk] = f2bf(sv);
        if (BIASDOT) bacc += sv * b1S[c * 32 + h2 * 16 + kk];
      }
#pragma unroll
      for (int kk = 8; kk < 16; kk++) {
        float sv = S[(h2 * 16 + kk) * 132 + n];
        p1[kk - 8] = f2bf(sv);
        if (BIASDOT) bacc += sv * b1S[c * 32 + h2 * 16 + kk];
      }
      *(ushort8v*)(&Bs[n * 40 + h2 * 16]) = p0;
      *(ushort8v*)(&Bs[n * 40 + h2 * 16 + 8]) = p1;
    }
    bar_lgkm();  // B3: Bs visible
    short8 bf[2], af[2];
#pragma unroll
    for (int ni = 0; ni < 2; ni++)
      bf[ni] = *(short8*)(&Bs[(w * 32 + ni * 16 + lrow) * 40 + kq * 8]);
#pragma unroll
    for (int mi = 0; mi < 2; mi++)
      af[mi] = *(short8*)(&As[(mi * 16 + lrow) * 40 + kq * 8]);
#pragma unroll
    for (int mi = 0; mi < 2; mi++)
#pragma unroll
      for (int ni = 0; ni < 2; ni++)
        acc[mi][ni] = __builtin_amdgcn_mfma_f32_16x16x32_bf16(
            af[mi], bf[ni], acc[mi][ni], 0, 0, 0);
  }
}

// ---------------------------------------------------------------------------
// wp4: all prep work, one launch, four roles (long roles dispatched FIRST):
//   [0,128):    W12  — W12[e] = W1@W2a (bf16 [e][n][a]) + bias2 = b1@W2a + b2
//   [128,256):  tvec — tvec[b] = tau_b@W2b (fp32, raw)
//   [256,768):  prep — W3 -> Wt3 bf16 k-blocked [e][kb][n][64]
//   768:        groupk — tiles for the grouped GEMM
// ---------------------------------------------------------------------------
__global__ __launch_bounds__(256) void wp4_kernel(
    const float* __restrict__ W1, const float* __restrict__ b1,
    const float* __restrict__ W2, const float* __restrict__ b2,
    const float* __restrict__ W3, const int* __restrict__ timesteps,
    const int* __restrict__ cat, unsigned short* __restrict__ Wt12,
    float* __restrict__ bias2G, float* __restrict__ tvec,
    unsigned short* __restrict__ Wt3, int* __restrict__ tiles,
    int* __restrict__ ntiles_out) {
  __shared__ __align__(16) unsigned char smem[33280];
  int tid = threadIdx.x;
  int bx = blockIdx.x;

  if (bx >= 256 && bx < 768) {
    // ---------------- prep role: W3 -> Wt3[e][kb][n][64] ----------------
    float* S2 = (float*)smem;  // [32][260] = 33280
    int id = bx - 256;
    int e = id >> 4, kb = (id >> 1) & 7, nh = id & 1;
    int kt = kb * 64, nt = nh * 256;
    ushort8v o[8];
#pragma unroll
    for (int h = 0; h < 2; h++) {
      if (h) __syncthreads();  // S2 free
#pragma unroll
      for (int j = 0; j < 16; j++) {  // 32 rows x 1KB rows
        int u = j * 256 + tid;
        int kk = u >> 7, cc = u & 127;
        float2 v = *(const float2*)(W3 + ((size_t)e * 512 + kt + h * 32 + kk) * NH +
                                    nt + cc * 2);
        *(float2*)(&S2[kk * 260 + cc * 2]) = v;
      }
      __syncthreads();  // S2 ready
      {  // column n=tid -> regs
        int n = tid;
#pragma unroll
        for (int q = 0; q < 4; q++) {
          ushort8v pk;
#pragma unroll
          for (int jj = 0; jj < 8; jj++)
            pk[jj] = f2bf(S2[(q * 8 + jj) * 260 + n]);
          o[h * 4 + q] = pk;
        }
      }
    }
    {  // write out: 128B per thread, 32KB contiguous per block
      int n = tid;
      unsigned short* dst = Wt3 + (((size_t)e * 8 + kb) * 512 + nt + n) * 64;
#pragma unroll
      for (int q = 0; q < 8; q++) *(ushort8v*)(dst + q * 8) = o[q];
    }
    return;
  }

  if (bx == 768) {
    // ---------------- groupk role ----------------
    int* cnt = (int*)smem;
    int* off = cnt + 32;
    int* cur = off + 32;
    int* order = cur + 32;
    if (tid < NE) cnt[tid] = 0;
    __syncthreads();
    int e = cat[tid];
    atomicAdd(&cnt[e], 1);
    __syncthreads();
    if (tid == 0) {
      int s = 0;
      for (int i = 0; i < NE; i++) { off[i] = s; cur[i] = s; s += cnt[i]; }
    }
    __syncthreads();
    int p = atomicAdd(&cur[e], 1);
    order[p] = tid;
    __syncthreads();
    if (tid == 0) {
      int nt = 0;
      for (int i = 0; i < NE; i++) {
        for (int j = 0; j < cnt[i]; j += 2) {
          tiles[3 * nt + 0] = i;
          tiles[3 * nt + 1] = order[off[i] + j];
          tiles[3 * nt + 2] = (j + 1 < cnt[i]) ? order[off[i] + j + 1] : -1;
          nt++;
        }
      }
      *ntiles_out = nt;
    }
    return;
  }

  // ---------------- long roles (N=128 per block) ----------------
  float* S           = (float*)smem;                     // [32][132] 16896
  unsigned short* Bs = (unsigned short*)(smem + 16896);  // [128][40] 10240
  unsigned short* As = (unsigned short*)(smem + 27136);  // [32][40]   2560
  float* b1S         = (float*)(smem + 29696);           // 2048 (W12)
  int* list          = (int*)(smem + 31872);             // 1024 (tvec)
  int* pcnt          = (int*)(smem + 32896);

  int w = tid >> 6, l = tid & 63;
  int lrow = l & 15, kq = l >> 4;

  if (bx < 128) {
    // ---- W12 role: (e, n-quarter) ----
    int e = bx >> 2, nq = bx & 3;
    const float* Wbase = W2 + ((size_t)e << 19) + nq * 128;  // W2a quarter
    const float* W1e = W1 + ((size_t)e << 14);
    {
      float2 v = *(const float2*)(b1 + (size_t)e * NH + tid * 2);
      *(float2*)(&b1S[tid * 2]) = v;
    }
    __syncthreads();  // b1S visible before stream (one-time)
    int aa = tid >> 3, seg = tid & 7;
    float4 pfW[2];
    f32x4 acc[2][2];
#pragma unroll
    for (int mi = 0; mi < 2; mi++)
#pragma unroll
      for (int ni = 0; ni < 2; ni++) acc[mi][ni] = (f32x4){0.f, 0.f, 0.f, 0.f};
    float bacc = 0.f;

    stream2<true>(
        Wbase, S, Bs, As, b1S, tid, w, lrow, kq, acc, bacc,
        [&](int c, int slot) {  // issue W1 chunk load
          pfW[slot] = *(const float4*)(W1e + (size_t)aa * NH + c * 32 + seg * 4);
        },
        [&](int c, int slot) {  // convert + store As
          ushort4v pk;
          pk[0] = f2bf(pfW[slot].x); pk[1] = f2bf(pfW[slot].y);
          pk[2] = f2bf(pfW[slot].z); pk[3] = f2bf(pfW[slot].w);
          *(ushort4v*)(&As[aa * 40 + seg * 4]) = pk;
        });

    __syncthreads();  // all MFMA reads done; reuse Bs as repack buffer
    unsigned short* Sb = Bs;  // [128 n][40 a]
#pragma unroll
    for (int mi = 0; mi < 2; mi++)
#pragma unroll
      for (int ni = 0; ni < 2; ni++)
#pragma unroll
        for (int r = 0; r < 4; r++)
          Sb[(w * 32 + ni * 16 + lrow) * 40 + mi * 16 + kq * 4 + r] =
              f2bf(acc[mi][ni][r]);
    {  // bias2: combine k-halves across lane pairs
      float bsum = bacc + __shfl_xor(bacc, 1);
      if ((tid & 1) == 0) {
        int n = tid >> 1;
        bias2G[(size_t)e * NH + nq * 128 + n] =
            bsum + b2[(size_t)e * NH + nq * 128 + n];
      }
    }
    __syncthreads();
    {  // Wt12 out: 32B per thread, coalesced
      int n = tid >> 1, q = tid & 1;
      unsigned short* dst = Wt12 + ((size_t)e * NH + nq * 128 + n) * NA + q * 16;
      *(ushort8v*)(dst) = *(ushort8v*)(&Sb[n * 40 + q * 16]);
      *(ushort8v*)(dst + 8) = *(ushort8v*)(&Sb[n * 40 + q * 16 + 8]);
    }
    return;
  }

  // ---- tvec role: (e, n-quarter) ----
  {
    int id = bx - 128;
    int e = id >> 2, nq = id & 3;
    const float* Wbase = W2 + ((size_t)e << 19) + ((size_t)512 * NH) + nq * 128;
    if (tid == 0) *pcnt = 0;
    __syncthreads();
    if (cat[tid] == e) { int p = atomicAdd(pcnt, 1); list[p] = tid; }
    __syncthreads();
    int c = *pcnt;
    if (c == 0) return;
    const float kLog = 0.035977893400931146f;  // ln(10000)/256
    int ss = tid >> 3, seg = tid & 7;

    for (int sg = 0; sg * 32 < c; sg++) {
      int si = sg * 32 + ss;
      float tv = (si < c) ? (float)timesteps[list[si]] : 0.f;  // per-thread reg
      f32x4 acc[2][2];
#pragma unroll
      for (int mi = 0; mi < 2; mi++)
#pragma unroll
        for (int ni = 0; ni < 2; ni++) acc[mi][ni] = (f32x4){0.f, 0.f, 0.f, 0.f};
      float dummy = 0.f;

      stream2<false>(
          Wbase, S, Bs, As, nullptr, tid, w, lrow, kq, acc, dummy,
          [](int, int) {},
          [&](int cch, int) {  // compute tau slice, store As
            ushort4v pk;
#pragma unroll
            for (int q = 0; q < 4; q++) {
              int kg = cch * 32 + seg * 4 + q;
              float f = expf(-(float)(kg & 255) * kLog);
              float ang = tv * f;
              pk[q] = f2bf((kg < 256) ? sinf(ang) : cosf(ang));
            }
            *(ushort4v*)(&As[ss * 40 + seg * 4]) = pk;
          });
#pragma unroll
      for (int mi = 0; mi < 2; mi++)
#pragma unroll
        for (int ni = 0; ni < 2; ni++)
#pragma unroll
          for (int r = 0; r < 4; r++) {
            int so = sg * 32 + mi * 16 + kq * 4 + r;
            if (so < c)
              tvec[(size_t)list[so] * NH + nq * 128 + w * 32 + ni * 16 + lrow] =
                  acc[mi][ni][r];
          }
    }
  }
}

// ---------------------------------------------------------------------------
// gemmh: hidden layer via FUSED weights. K=32 (one MFMA per fragment):
//   Hb[b*64+t][n] = swish( actions[b][t] @ Wt12[e] + tvec[b][n] + bias2[e][n] )
// ---------------------------------------------------------------------------
__global__ __launch_bounds__(256) void gemmh_kernel(
    const float* __restrict__ actions, const unsigned short* __restrict__ Wt12,
    const float* __restrict__ tvec, const float* __restrict__ bias2,
    const int* __restrict__ cat_ids, unsigned short* __restrict__ Hb) {
  __shared__ __align__(16) unsigned char smem[16384 + 5120 + 33792];
  unsigned short* Ws = (unsigned short*)smem;                   // [256][32] swizzled
  unsigned short* As = (unsigned short*)(smem + 16384);         // [64][40]
  unsigned short* Ts = (unsigned short*)(smem + 16384 + 5120);  // [64][264]

  int b = blockIdx.y, h = blockIdx.x;
  int tid = threadIdx.x;
  int e = cat_ids[b];

  {  // async stage Wt12[e][h*256 .. +256][0..32] -> Ws (chunk swizzle)
    const unsigned short* wsrc = Wt12 + ((size_t)e * NH + h * 256) * NA;
#pragma unroll
    for (int j = 0; j < 4; j++) {
      int u = j * 256 + tid;
      int n = u >> 2, p = u & 3;
      int ch = p ^ ((n >> 1) & 3);
      gl2lds16(wsrc + (size_t)n * NA + ch * 8,
               Ws + (size_t)(j * 256 + (tid & 448)) * 8);
    }
  }
  {  // stage actions (64x32 f32 -> bf16), padded stride 40
    int row = tid >> 2, seg = tid & 3;
    const float* src = actions + (size_t)(b * NT + row) * NA + seg * 8;
    float4 v0 = *(const float4*)(src);
    float4 v1 = *(const float4*)(src + 4);
    *(ushort8v*)(&As[row * 40 + seg * 8]) = cvt8(v0, v1);
  }
  __syncthreads();

  int w = tid >> 6, l = tid & 63;
  int lrow = l & 15, kq = l >> 4;
  short8 af = *(short8*)(&As[(w * 16 + lrow) * 40 + kq * 8]);
  f32x4 zero = {0.f, 0.f, 0.f, 0.f};
  f32x4 acc[16];
#pragma unroll
  for (int ni = 0; ni < 16; ni++) {
    int nn = ni * 16 + lrow;
    int p = kq ^ ((nn >> 1) & 3);
    short8 bfv = *(short8*)(&Ws[nn * 32 + p * 8]);
    acc[ni] = __builtin_amdgcn_mfma_f32_16x16x32_bf16(af, bfv, zero, 0, 0, 0);
  }
#pragma unroll
  for (int ni = 0; ni < 16; ni++) {
    int colL = ni * 16 + lrow;
    float bv = tvec[(size_t)b * NH + h * 256 + colL] +
               bias2[(size_t)e * NH + h * 256 + colL];
#pragma unroll
    for (int r = 0; r < 4; r++) {
      int row = w * 16 + kq * 4 + r;
      float v = acc[ni][r] + bv;
      v = v / (1.0f + __expf(-v));  // swish
      Ts[row * 264 + colL] = f2bf(v);
    }
  }
  __syncthreads();
#pragma unroll
  for (int i = 0; i < 8; i++) {  // coalesced Hb rows
    int u = i * 256 + tid;
    int t = u >> 5, c4 = u & 31;
    uint4 v = *(uint4*)(&Ts[t * 264 + c4 * 8]);
    *(uint4*)(Hb + ((size_t)(b * NT + t)) * NH + h * 256 + c4 * 8) = v;
  }
}

// ---------------------------------------------------------------------------
// Grouped GEMM, 2-phase double-buffered pipeline, counted vmcnt(6).
// B-side reads the k-blocked Wt3 layout [e][kb][n][64]: 8KB contiguous per tile.
// ---------------------------------------------------------------------------
template <int KTOT, bool HASTAU, bool SWISH, bool OUT_BF16>
__global__ __launch_bounds__(256) void gemm2_kernel(
    const unsigned short* __restrict__ Xa, const unsigned short* __restrict__ Xt,
    const unsigned short* __restrict__ Wt, const float* __restrict__ bias,
    void* __restrict__ Yv, const int* __restrict__ tiles,
    const int* __restrict__ pntiles) {
  __shared__ __align__(16) unsigned char smem[49152];  // 2 x (As 16K + Bs 8K)

  int ti = blockIdx.y;
  if (ti >= *pntiles) return;
  int n0 = blockIdx.x * 64;
  int e = tiles[3 * ti], s0 = tiles[3 * ti + 1], s1 = tiles[3 * ti + 2];
  int s1v = (s1 < 0) ? s0 : s1;

  int tid = threadIdx.x;
  int l = tid & 63;
  int wr = (tid >> 7), wc = (tid >> 6) & 1;
  int lrow = l & 15, kq = l >> 4;

  constexpr int NIT = KTOT / 64;

  auto stage = [&](int it, int buf) {
    unsigned short* As = (unsigned short*)(smem + buf * 24576);
    unsigned short* Bs = (unsigned short*)(smem + buf * 24576 + 16384);
    int k0 = it * 64;
#pragma unroll
    for (int j = 0; j < 4; j++) {
      int u = j * 256 + tid;
      int row = u >> 3, p = u & 7;
      int ch = p ^ (row & 7);
      int kk = k0 + ch * 8;
      int s = (row < 64) ? s0 : s1v;
      const unsigned short* src;
      if (HASTAU && kk >= 512)
        src = Xt + (size_t)s * NH + (kk - 512);
      else
        src = Xa + ((size_t)(s * NT + (row & 63))) * NH + kk;
      gl2lds16(src, As + (size_t)(j * 256 + (tid & 448)) * 8);
    }
#pragma unroll
    for (int j = 0; j < 2; j++) {
      int u = j * 256 + tid;
      int n = u >> 3, p = u & 7;
      int ch = p ^ (n & 7);
      gl2lds16(Wt + (((size_t)e * 8 + it) * 512 + n0 + n) * 64 + ch * 8,
               Bs + (size_t)(j * 256 + (tid & 448)) * 8);
    }
  };

  f32x4 acc[4][2];
#pragma unroll
  for (int mi = 0; mi < 4; mi++)
#pragma unroll
    for (int ni = 0; ni < 2; ni++) acc[mi][ni] = (f32x4){0.f, 0.f, 0.f, 0.f};

  stage(0, 0);
  stage(1, 1);

  for (int t = 0; t < NIT; t++) {
    int cur = t & 1;
    unsigned short* As = (unsigned short*)(smem + cur * 24576);
    unsigned short* Bs = (unsigned short*)(smem + cur * 24576 + 16384);

    if (t + 1 < NIT) {
      asm volatile("s_waitcnt vmcnt(6)" ::: "memory");
    } else {
      asm volatile("s_waitcnt vmcnt(0)" ::: "memory");
    }
    __builtin_amdgcn_sched_barrier(0);
    __builtin_amdgcn_s_barrier();
    __builtin_amdgcn_sched_barrier(0);

    short8 afr[2][4], bfr[2][2];
#pragma unroll
    for (int s2 = 0; s2 < 2; s2++) {
#pragma unroll
      for (int mi = 0; mi < 4; mi++) {
        int row = wr * 64 + mi * 16 + lrow;
        int p = (s2 * 4 + kq) ^ (row & 7);
        afr[s2][mi] = *(short8*)(&As[row * 64 + p * 8]);
      }
#pragma unroll
      for (int ni = 0; ni < 2; ni++) {
        int n = wc * 32 + ni * 16 + lrow;
        int p = (s2 * 4 + kq) ^ (n & 7);
        bfr[s2][ni] = *(short8*)(&Bs[n * 64 + p * 8]);
      }
    }
    asm volatile("s_waitcnt lgkmcnt(0)" ::: "memory");
    __builtin_amdgcn_sched_barrier(0);
    __builtin_amdgcn_s_barrier();
    __builtin_amdgcn_sched_barrier(0);

    if (t + 2 < NIT) stage(t + 2, cur);

#pragma unroll
    for (int s2 = 0; s2 < 2; s2++)
#pragma unroll
      for (int mi = 0; mi < 4; mi++)
#pragma unroll
        for (int ni = 0; ni < 2; ni++)
          acc[mi][ni] = __builtin_amdgcn_mfma_f32_16x16x32_bf16(
              afr[s2][mi], bfr[s2][ni], acc[mi][ni], 0, 0, 0);
  }
  __syncthreads();

#pragma unroll
  for (int ni = 0; ni < 2; ni++) {
    int colL = wc * 32 + ni * 16 + lrow;
    float bv = bias[(size_t)e * NH + n0 + colL];
#pragma unroll
    for (int mi = 0; mi < 4; mi++) {
#pragma unroll
      for (int r = 0; r < 4; r++) {
        int row = wr * 64 + mi * 16 + kq * 4 + r;
        float v = acc[mi][ni][r] + bv;
        if (SWISH) v = v / (1.0f + __expf(-v));
        if (OUT_BF16)
          ((unsigned short*)smem)[row * 80 + colL] = f2bf(v);
        else
          ((float*)smem)[row * 68 + colL] = v;
      }
    }
  }
  __syncthreads();
  if (OUT_BF16) {
    unsigned short* Y = (unsigned short*)Yv;
#pragma unroll
    for (int i = 0; i < 4; i++) {
      int u = i * 256 + tid;
      int row = u >> 3, c = u & 7;
      if (row >= 64 && s1 < 0) continue;
      int s = (row < 64) ? s0 : s1;
      uint4 v = *(uint4*)(&((unsigned short*)smem)[row * 80 + c * 8]);
      *(uint4*)(Y + ((size_t)(s * NT + (row & 63))) * NH + n0 + c * 8) = v;
    }
  } else {
    float* Y = (float*)Yv;
#pragma unroll
    for (int i = 0; i < 8; i++) {
      int u = i * 256 + tid;
      int row = u >> 4, c = u & 15;
      if (row >= 64 && s1 < 0) continue;
      int s = (row < 64) ? s0 : s1;
      uint4 v = *(uint4*)(&((float*)smem)[row * 68 + c * 4]);
      *(uint4*)(Y + ((size_t)(s * NT + (row & 63))) * NH + n0 + c * 4) = v;
    }
  }
}

// ---------------------------------------------------------------------------
extern "C" void kernel_launch(void* const* d_in, const int* in_sizes, int n_in,
                              void* d_out, int out_size, void* d_ws, size_t ws_size,
                              hipStream_t stream) {
  const float* actions   = (const float*)d_in[0];
  const int*   timesteps = (const int*)d_in[1];
  const int*   cat_ids   = (const int*)d_in[2];
  const float* W1 = (const float*)d_in[3];
  const float* b1 = (const float*)d_in[4];
  const float* W2 = (const float*)d_in[5];
  const float* b2 = (const float*)d_in[6];
  const float* W3 = (const float*)d_in[7];
  const float* b3 = (const float*)d_in[8];

  // ws: Hb 16MB | Wt3 16MB (k-blocked) | Wt12 1MB | tvec 512KB | bias2 | tiles
  unsigned short* Hb   = (unsigned short*)d_ws;
  unsigned short* Wt3  = (unsigned short*)((char*)d_ws + (size_t)16777216);
  unsigned short* Wt12 = (unsigned short*)((char*)d_ws + (size_t)33554432);
  float* tvec  = (float*)((char*)d_ws + (size_t)34603008);
  float* bias2 = (float*)((char*)d_ws + (size_t)35127296);
  int* tiles   = (int*)((char*)d_ws + (size_t)35192832);
  int* ntiles  = tiles + 3 * MAXTILES;

  wp4_kernel<<<769, 256, 0, stream>>>(W1, b1, W2, b2, W3, timesteps, cat_ids,
                                      Wt12, bias2, tvec, Wt3, tiles, ntiles);
  gemmh_kernel<<<dim3(2, NB), 256, 0, stream>>>(actions, Wt12, tvec, bias2,
                                                cat_ids, Hb);
  gemm2_kernel<512, false, false, false><<<dim3(8, MAXTILES), 256, 0, stream>>>(
      Hb, nullptr, Wt3, b3, d_out, tiles, ntiles);
}